// Round 11
// baseline (745.211 us; speedup 1.0000x reference)
//
#include <hip/hip_runtime.h>
#include <math.h>
#include <float.h>

#define BGRAPH 16
#define NPTS   2048
#define CDIM   16
#define ODIM   64
#define KNN    16
#define NTOT   (BGRAPH*NPTS)     // 32768
#define NEDGE  (NTOT*KNN)        // 524288
#define EPSBN  1e-5f
#define NBLK_E 2048              // blocks for edge-stat passes
#define NPW    4                 // nodes per wave in edge-stat passes

// ---------------- P = x@W1b, Q = x@(W1a-W1b)+b1, sq = rowsum(x*x) ----------
// Also zeroes the two last-block counters (runs strictly before stats passes).
__global__ __launch_bounds__(256) void pq_kernel(
    const float* __restrict__ x, const float* __restrict__ W1,
    const float* __restrict__ b1,
    float* __restrict__ P, float* __restrict__ Q, float* __restrict__ sq,
    int* __restrict__ cnts) {
  if (blockIdx.x == 0 && threadIdx.x < 2) cnts[threadIdx.x] = 0;
  int lane = threadIdx.x & 63;
  int nin  = threadIdx.x >> 6;           // node within block (0..3)
  int node = blockIdx.x * 4 + nin;
  __shared__ float xs[4][CDIM];
  if (threadIdx.x < 4*CDIM) {
    int n = threadIdx.x / CDIM, c = threadIdx.x % CDIM;
    xs[n][c] = x[(blockIdx.x*4 + n)*CDIM + c];
  }
  __syncthreads();
  float p = 0.f, q = b1[lane];
  #pragma unroll
  for (int c = 0; c < CDIM; ++c) {
    float xv = xs[nin][c];
    float wb = W1[(c+CDIM)*ODIM + lane];
    float wa = W1[c*ODIM + lane];
    p += xv * wb;
    q += xv * (wa - wb);
  }
  P[node*ODIM + lane] = p;
  Q[node*ODIM + lane] = q;
  if (lane == 0) {
    float s = 0.f;
    #pragma unroll
    for (int c = 0; c < CDIM; ++c) { float xv = xs[nin][c]; s += xv*xv; }
    sq[node] = s;
  }
}

// ---------------- kNN: one row per wave, all state in registers -------------
// FROZEN round-1 kernel (measured r6/r9: ~114us, VGPR=60, WRITE=2MB). Every
// R=2 attempt (r2-r5) put the distance array in scratch (2GB WRITE, 7-11x
// slower). Flat d[32] + ~56 VGPR demand is the proven-promotable shape on
// this compiler. Do not increase per-thread state here.
#define KROWS 4
__device__ __forceinline__ unsigned long long packkey(float dv, int j) {
  unsigned ub = __float_as_uint(dv);
  ub ^= ((unsigned)((int)ub >> 31)) | 0x80000000u;   // monotone f32->u32
  return (((unsigned long long)ub) << 32) | (unsigned)j;
}

__global__ __launch_bounds__(256, 4) void knn_kernel(
    const float* __restrict__ x, const float* __restrict__ sq,
    int* __restrict__ idxOut) {
  __shared__ float sT16[CDIM][256];                 // transposed tile, 16 KB
  __shared__ unsigned long long skey[4][64];        // per-wave survivor keys
  __shared__ int scnt[4];
  const int tid  = threadIdx.x;
  const int lane = tid & 63;
  const int w    = tid >> 6;
  const int blocksPerGraph = NPTS / KROWS;          // 512
  const int g     = blockIdx.x / blocksPerGraph;
  const int rb    = (blockIdx.x % blocksPerGraph) * KROWS;
  const int gbase = g * NPTS;
  const int r0    = rb + w;                         // this wave's single row

  float tg[CDIM]; float tsq;
  {
    const float4* tp = (const float4*)(x + (size_t)(gbase + r0)*CDIM);
    float4 t0 = tp[0], t1 = tp[1], t2 = tp[2], t3 = tp[3];
    tg[0]=t0.x; tg[1]=t0.y; tg[2]=t0.z; tg[3]=t0.w;
    tg[4]=t1.x; tg[5]=t1.y; tg[6]=t1.z; tg[7]=t1.w;
    tg[8]=t2.x; tg[9]=t2.y; tg[10]=t2.z; tg[11]=t2.w;
    tg[12]=t3.x; tg[13]=t3.y; tg[14]=t3.z; tg[15]=t3.w;
    tsq = sq[gbase + r0];
  }

  float d[32];

  // prefetch tile 0 into regs
  float4 a0, a1, a2, a3;
  {
    const float4* xp = (const float4*)(x + (size_t)(gbase + tid)*CDIM);
    a0 = xp[0]; a1 = xp[1]; a2 = xp[2]; a3 = xp[3];
  }

  for (int t = 0; t < NPTS/256; ++t) {
    __syncthreads();                                // prev tile reads done
    sT16[0][tid]=a0.x;  sT16[1][tid]=a0.y;  sT16[2][tid]=a0.z;  sT16[3][tid]=a0.w;
    sT16[4][tid]=a1.x;  sT16[5][tid]=a1.y;  sT16[6][tid]=a1.z;  sT16[7][tid]=a1.w;
    sT16[8][tid]=a2.x;  sT16[9][tid]=a2.y;  sT16[10][tid]=a2.z; sT16[11][tid]=a2.w;
    sT16[12][tid]=a3.x; sT16[13][tid]=a3.y; sT16[14][tid]=a3.z; sT16[15][tid]=a3.w;
    __syncthreads();
    if (t < NPTS/256 - 1) {                         // issue next-tile loads early
      const float4* xp = (const float4*)(x + (size_t)(gbase + (t+1)*256 + tid)*CDIM);
      a0 = xp[0]; a1 = xp[1]; a2 = xp[2]; a3 = xp[3];
    }

    float4 sq4 = *(const float4*)(sq + gbase + t*256 + 4*lane);
    float sqv[4] = {sq4.x, sq4.y, sq4.z, sq4.w};

    float dot[4] = {0.f,0.f,0.f,0.f};
    #pragma unroll
    for (int c = 0; c < CDIM; ++c) {
      float4 cv = *(const float4*)(&sT16[c][4*lane]);
      float cvv[4]; cvv[0]=cv.x; cvv[1]=cv.y; cvv[2]=cv.z; cvv[3]=cv.w;
      float xv = tg[c];
      #pragma unroll
      for (int rr = 0; rr < 4; ++rr)
        dot[rr] += xv * cvv[rr];
    }
    #pragma unroll
    for (int rr = 0; rr < 4; ++rr)
      d[t*4 + rr] = tsq + sqv[rr] - 2.f*dot[rr];
  }

  {
    float lmin = d[0];
    #pragma unroll
    for (int s = 1; s < 32; ++s) lmin = fminf(lmin, d[s]);

    float v = lmin;
    #pragma unroll
    for (int k = 2; k <= 64; k <<= 1) {
      #pragma unroll
      for (int j = k >> 1; j > 0; j >>= 1) {
        float o = __shfl_xor(v, j);
        bool asc   = ((lane & k) == 0);
        bool lower = ((lane & j) == 0);
        float mn = fminf(v, o), mx = fmaxf(v, o);
        v = (asc == lower) ? mn : mx;
      }
    }
    float T = __shfl(v, 15);

    if (lane == 0) scnt[w] = 0;
    #pragma unroll
    for (int s = 0; s < 32; ++s) {
      if (d[s] <= T) {
        int p = atomicAdd(&scnt[w], 1);
        if (p < 64) {
          int j = (s >> 2)*256 + 4*lane + (s & 3);
          skey[w][p] = packkey(d[s], j);
        }
      }
    }
    int M = scnt[w];
    int row = gbase + r0;

    if (M <= 64) {
      unsigned long long key = (lane < M) ? skey[w][lane] : ~0ull;
      #pragma unroll
      for (int k = 2; k <= 64; k <<= 1) {
        #pragma unroll
        for (int j = k >> 1; j > 0; j >>= 1) {
          unsigned long long o = __shfl_xor(key, j);
          bool asc   = ((lane & k) == 0);
          bool lower = ((lane & j) == 0);
          unsigned long long mn = (key < o) ? key : o;
          unsigned long long mx = (key < o) ? o : key;
          key = (asc == lower) ? mn : mx;
        }
      }
      if (lane < KNN)
        idxOut[(size_t)row*KNN + lane] = gbase + (int)(key & 0xffffffffu);
    } else {
      for (int sel = 0; sel < KNN; ++sel) {
        unsigned long long lb = ~0ull;
        #pragma unroll
        for (int s = 0; s < 32; ++s) {
          int j = (s >> 2)*256 + 4*lane + (s & 3);
          unsigned long long ks = packkey(d[s], j);
          if (ks < lb) lb = ks;
        }
        #pragma unroll
        for (int off = 32; off > 0; off >>= 1) {
          unsigned long long o = __shfl_xor(lb, off);
          if (o < lb) lb = o;
        }
        if (lane == 0)
          idxOut[(size_t)row*KNN + sel] = gbase + (int)(lb & 0xffffffffu);
        #pragma unroll
        for (int s = 0; s < 32; ++s) {
          int j = (s >> 2)*256 + 4*lane + (s & 3);
          if (packkey(d[s], j) == lb) d[s] = FLT_MAX;
        }
      }
    }
  }
}

// ---------------- stats pass 1 + last-block fin1 ----------------------------
// GROUPED body (r9-verified). Tail: publish partials, __threadfence(),
// atomicAdd a counter; the LAST block (no one waits) reduces pbuf and
// computes scale/shift inline. Removes the fin1 dispatch + launch gap.
// (r10 lesson: cooperative grid.sync costs ~100us/sync on MI355X — last-
// block-done has no spin, no grid-wide wait.)
__global__ __launch_bounds__(256) void stats1f_kernel(
    const float* __restrict__ P, const float* __restrict__ Q,
    const int* __restrict__ idx,
    const float* __restrict__ g1, const float* __restrict__ be1,
    float* __restrict__ pbuf, float* __restrict__ scale,
    float* __restrict__ shift, int* __restrict__ cnt) {
  int tid  = threadIdx.x;
  int lane = tid & 63;
  int wid  = tid >> 6;
  int grp  = lane >> 4;                 // edge-quad slot 0..3
  int p    = lane & 15;                 // channel quad 0..15
  int gw   = blockIdx.x * 4 + wid;
  int n0 = gw * NPW;
  float4 s4  = {0.f,0.f,0.f,0.f};
  float4 ss4 = {0.f,0.f,0.f,0.f};
  #pragma unroll
  for (int ii = 0; ii < NPW; ++ii) {
    int i = n0 + ii;
    float4 q4 = *(const float4*)(Q + (size_t)i*ODIM + 4*p);
    int4 j4 = *(const int4*)(idx + (size_t)i*KNN + 4*grp);
    {
      float4 v = *(const float4*)(P + (size_t)j4.x*ODIM + 4*p);
      float hx=q4.x+v.x, hy=q4.y+v.y, hz=q4.z+v.z, hw=q4.w+v.w;
      s4.x+=hx; s4.y+=hy; s4.z+=hz; s4.w+=hw;
      ss4.x+=hx*hx; ss4.y+=hy*hy; ss4.z+=hz*hz; ss4.w+=hw*hw;
    }
    {
      float4 v = *(const float4*)(P + (size_t)j4.y*ODIM + 4*p);
      float hx=q4.x+v.x, hy=q4.y+v.y, hz=q4.z+v.z, hw=q4.w+v.w;
      s4.x+=hx; s4.y+=hy; s4.z+=hz; s4.w+=hw;
      ss4.x+=hx*hx; ss4.y+=hy*hy; ss4.z+=hz*hz; ss4.w+=hw*hw;
    }
    {
      float4 v = *(const float4*)(P + (size_t)j4.z*ODIM + 4*p);
      float hx=q4.x+v.x, hy=q4.y+v.y, hz=q4.z+v.z, hw=q4.w+v.w;
      s4.x+=hx; s4.y+=hy; s4.z+=hz; s4.w+=hw;
      ss4.x+=hx*hx; ss4.y+=hy*hy; ss4.z+=hz*hz; ss4.w+=hw*hw;
    }
    {
      float4 v = *(const float4*)(P + (size_t)j4.w*ODIM + 4*p);
      float hx=q4.x+v.x, hy=q4.y+v.y, hz=q4.z+v.z, hw=q4.w+v.w;
      s4.x+=hx; s4.y+=hy; s4.z+=hz; s4.w+=hw;
      ss4.x+=hx*hx; ss4.y+=hy*hy; ss4.z+=hz*hz; ss4.w+=hw*hw;
    }
  }
  // cross-group reduce (each group's partial enters ONCE; xor16/32 cross
  // group boundaries only — r7 post-mortem)
  s4.x  += __shfl_xor(s4.x,16);  s4.x  += __shfl_xor(s4.x,32);
  s4.y  += __shfl_xor(s4.y,16);  s4.y  += __shfl_xor(s4.y,32);
  s4.z  += __shfl_xor(s4.z,16);  s4.z  += __shfl_xor(s4.z,32);
  s4.w  += __shfl_xor(s4.w,16);  s4.w  += __shfl_xor(s4.w,32);
  ss4.x += __shfl_xor(ss4.x,16); ss4.x += __shfl_xor(ss4.x,32);
  ss4.y += __shfl_xor(ss4.y,16); ss4.y += __shfl_xor(ss4.y,32);
  ss4.z += __shfl_xor(ss4.z,16); ss4.z += __shfl_xor(ss4.z,32);
  ss4.w += __shfl_xor(ss4.w,16); ss4.w += __shfl_xor(ss4.w,32);
  __shared__ float ls[4][ODIM], lss[4][ODIM];
  if (grp == 0) {
    *(float4*)&ls[wid][4*p]  = s4;
    *(float4*)&lss[wid][4*p] = ss4;
  }
  __syncthreads();
  if (tid < ODIM) {
    float a = ls[0][tid] + ls[1][tid] + ls[2][tid] + ls[3][tid];
    pbuf[(size_t)tid*NBLK_E + blockIdx.x] = a;
  } else if (tid < 2*ODIM) {
    int o = tid - ODIM;
    float a = lss[0][o] + lss[1][o] + lss[2][o] + lss[3][o];
    pbuf[(size_t)(ODIM+o)*NBLK_E + blockIdx.x] = a;
  }

  // ---- last-block fin1 ----
  __threadfence();                      // publish pbuf writes device-wide
  __shared__ int lastFlag;
  if (tid == 0) lastFlag = (atomicAdd(cnt, 1) == NBLK_E - 1);
  __syncthreads();
  if (!lastFlag) return;
  __threadfence();                      // acquire: see all blocks' pbuf
  int r = tid >> 1;                     // row 0..127 (sum rows 0..63, ss 64..127)
  int h = tid & 1;
  const float4* pr = (const float4*)(pbuf + (size_t)r*NBLK_E) + h*(NBLK_E/8);
  float s = 0.f;
  for (int t = 0; t < NBLK_E/8; ++t) { float4 v4 = pr[t]; s += v4.x+v4.y+v4.z+v4.w; }
  s += __shfl_xor(s, 1);                // pair lanes 2r,2r+1 (same wave)
  __shared__ float red[128];
  if (h == 0) red[r] = s;
  __syncthreads();
  if (tid < ODIM) {
    int o = tid;
    float mu  = red[o] / (float)NEDGE;
    float var = red[ODIM+o] / (float)NEDGE - mu*mu;
    float inv = 1.0f / sqrtf(var + EPSBN);
    float sc = g1[o] * inv;
    scale[o] = sc;
    shift[o] = be1[o] - mu * sc;
  }
}

// ---------------- stats pass 2 + last-block fin2 ----------------------------
__global__ __launch_bounds__(256) void stats2f_kernel(
    const float* __restrict__ P, const float* __restrict__ Q,
    const int* __restrict__ idx, const float* __restrict__ scale,
    const float* __restrict__ shift, const float* __restrict__ Wg,
    const float* __restrict__ bg, const float* __restrict__ gg,
    const float* __restrict__ beg, float* __restrict__ gtbuf,
    float* __restrict__ gpart, float* __restrict__ gsc,
    int* __restrict__ cnt) {
  int tid  = threadIdx.x;
  int lane = tid & 63;
  int wid  = tid >> 6;
  int grp  = lane >> 4;                 // edge-quad slot
  int p    = lane & 15;                 // channel quad
  int gw   = blockIdx.x * 4 + wid;
  int n0 = gw * NPW;
  float4 sc4 = *(const float4*)(scale + 4*p);
  float4 sh4 = *(const float4*)(shift + 4*p);
  float4 wg4 = *(const float4*)(Wg + 4*p);
  float bgv = bg[0];
  float s = 0.f, ss = 0.f;
  #pragma unroll
  for (int ii = 0; ii < NPW; ++ii) {
    int i = n0 + ii;
    float4 q4 = *(const float4*)(Q + (size_t)i*ODIM + 4*p);
    int4 j4 = *(const int4*)(idx + (size_t)i*KNN + 4*grp);
    #pragma unroll
    for (int e = 0; e < 4; ++e) {
      int j = (e==0) ? j4.x : (e==1) ? j4.y : (e==2) ? j4.z : j4.w;
      float4 p4 = *(const float4*)(P + (size_t)j*ODIM + 4*p);
      float zx = (q4.x + p4.x)*sc4.x + sh4.x;
      float zy = (q4.y + p4.y)*sc4.y + sh4.y;
      float zz = (q4.z + p4.z)*sc4.z + sh4.z;
      float zw = (q4.w + p4.w)*sc4.w + sh4.w;
      float v = (zx/(1.f+expf(-zx)))*wg4.x
              + (zy/(1.f+expf(-zy)))*wg4.y
              + (zz/(1.f+expf(-zz)))*wg4.z
              + (zw/(1.f+expf(-zw)))*wg4.w;
      v += __shfl_xor(v, 1);
      v += __shfl_xor(v, 2);
      v += __shfl_xor(v, 4);
      v += __shfl_xor(v, 8);            // group-wide sum over 64 channels
      float gt = v + bgv;
      if (p == 0) gtbuf[(size_t)i*KNN + 4*grp + e] = gt;
      s += gt; ss += gt*gt;             // per-group partial
    }
  }
  // each group's total enters exactly once (xor16/32 cross groups only)
  s  += __shfl_xor(s, 16);  s  += __shfl_xor(s, 32);
  ss += __shfl_xor(ss, 16); ss += __shfl_xor(ss, 32);
  __shared__ float pw[4], pws[4];
  if (lane == 0) { pw[wid] = s; pws[wid] = ss; }
  __syncthreads();
  if (tid == 0) {
    gpart[2*blockIdx.x]   = pw[0]+pw[1]+pw[2]+pw[3];
    gpart[2*blockIdx.x+1] = pws[0]+pws[1]+pws[2]+pws[3];
  }

  // ---- last-block fin2 ----
  __threadfence();
  __shared__ int lastFlag;
  if (tid == 0) lastFlag = (atomicAdd(cnt, 1) == NBLK_E - 1);
  __syncthreads();
  if (!lastFlag) return;
  __threadfence();
  float rs = 0.f, rss = 0.f;
  for (int t = tid; t < NBLK_E; t += 256) { rs += gpart[2*t]; rss += gpart[2*t+1]; }
  __shared__ float as[256], bs[256];
  as[tid] = rs; bs[tid] = rss;
  __syncthreads();
  #pragma unroll
  for (int st = 128; st > 0; st >>= 1) {
    if (tid < st) { as[tid] += as[tid+st]; bs[tid] += bs[tid+st]; }
    __syncthreads();
  }
  if (tid == 0) {
    float mu  = as[0] / (float)NEDGE;
    float var = bs[0] / (float)NEDGE - mu*mu;
    float inv = 1.f / sqrtf(var + EPSBN);
    float sg = gg[0] * inv;
    gsc[0] = sg; gsc[1] = beg[0] - mu * sg;
  }
}

// ---------------- final: hn, gate from gtbuf, softmax over K, weighted sum --
// GROUPED (r9-verified): 1 node per wave; group owns an edge-quad; lane owns
// 4 channels. Gate softmax via cross-group shfl; output written by group 0.
__global__ __launch_bounds__(256) void final_kernel(
    const float* __restrict__ P, const float* __restrict__ Q,
    const int* __restrict__ idx, const float* __restrict__ scale,
    const float* __restrict__ shift, const float* __restrict__ gtbuf,
    const float* __restrict__ gsc, float* __restrict__ out) {
  int lane = threadIdx.x & 63;
  int wid  = threadIdx.x >> 6;
  int grp  = lane >> 4;
  int p    = lane & 15;
  int i = blockIdx.x * 4 + wid;
  float4 sc4 = *(const float4*)(scale + 4*p);
  float4 sh4 = *(const float4*)(shift + 4*p);
  float gscale = gsc[0], gshift = gsc[1];
  float4 q4 = *(const float4*)(Q + (size_t)i*ODIM + 4*p);
  int4   j4 = *(const int4*)(idx + (size_t)i*KNN + 4*grp);
  float4 g4 = *(const float4*)(gtbuf + (size_t)i*KNN + 4*grp);

  float z0 = g4.x*gscale + gshift, z1 = g4.y*gscale + gshift;
  float z2 = g4.z*gscale + gshift, z3 = g4.w*gscale + gshift;
  float gt0 = z0/(1.f+expf(-z0)), gt1 = z1/(1.f+expf(-z1));
  float gt2 = z2/(1.f+expf(-z2)), gt3 = z3/(1.f+expf(-z3));
  float m = fmaxf(fmaxf(gt0, gt1), fmaxf(gt2, gt3));
  m = fmaxf(m, __shfl_xor(m, 16));
  m = fmaxf(m, __shfl_xor(m, 32));
  float e0 = expf(gt0-m), e1 = expf(gt1-m), e2 = expf(gt2-m), e3 = expf(gt3-m);
  float se = e0+e1+e2+e3;
  se += __shfl_xor(se, 16);
  se += __shfl_xor(se, 32);
  float invs = 1.f / se;
  float a0 = e0*invs, a1 = e1*invs, a2 = e2*invs, a3 = e3*invs;

  float4 acc = {0.f,0.f,0.f,0.f};
  {
    float4 v = *(const float4*)(P + (size_t)j4.x*ODIM + 4*p);
    float zx=(q4.x+v.x)*sc4.x+sh4.x, zy=(q4.y+v.y)*sc4.y+sh4.y;
    float zz=(q4.z+v.z)*sc4.z+sh4.z, zw=(q4.w+v.w)*sc4.w+sh4.w;
    acc.x += a0*(zx/(1.f+expf(-zx))); acc.y += a0*(zy/(1.f+expf(-zy)));
    acc.z += a0*(zz/(1.f+expf(-zz))); acc.w += a0*(zw/(1.f+expf(-zw)));
  }
  {
    float4 v = *(const float4*)(P + (size_t)j4.y*ODIM + 4*p);
    float zx=(q4.x+v.x)*sc4.x+sh4.x, zy=(q4.y+v.y)*sc4.y+sh4.y;
    float zz=(q4.z+v.z)*sc4.z+sh4.z, zw=(q4.w+v.w)*sc4.w+sh4.w;
    acc.x += a1*(zx/(1.f+expf(-zx))); acc.y += a1*(zy/(1.f+expf(-zy)));
    acc.z += a1*(zz/(1.f+expf(-zz))); acc.w += a1*(zw/(1.f+expf(-zw)));
  }
  {
    float4 v = *(const float4*)(P + (size_t)j4.z*ODIM + 4*p);
    float zx=(q4.x+v.x)*sc4.x+sh4.x, zy=(q4.y+v.y)*sc4.y+sh4.y;
    float zz=(q4.z+v.z)*sc4.z+sh4.z, zw=(q4.w+v.w)*sc4.w+sh4.w;
    acc.x += a2*(zx/(1.f+expf(-zx))); acc.y += a2*(zy/(1.f+expf(-zy)));
    acc.z += a2*(zz/(1.f+expf(-zz))); acc.w += a2*(zw/(1.f+expf(-zw)));
  }
  {
    float4 v = *(const float4*)(P + (size_t)j4.w*ODIM + 4*p);
    float zx=(q4.x+v.x)*sc4.x+sh4.x, zy=(q4.y+v.y)*sc4.y+sh4.y;
    float zz=(q4.z+v.z)*sc4.z+sh4.z, zw=(q4.w+v.w)*sc4.w+sh4.w;
    acc.x += a3*(zx/(1.f+expf(-zx))); acc.y += a3*(zy/(1.f+expf(-zy)));
    acc.z += a3*(zz/(1.f+expf(-zz))); acc.w += a3*(zw/(1.f+expf(-zw)));
  }
  acc.x += __shfl_xor(acc.x,16); acc.x += __shfl_xor(acc.x,32);
  acc.y += __shfl_xor(acc.y,16); acc.y += __shfl_xor(acc.y,32);
  acc.z += __shfl_xor(acc.z,16); acc.z += __shfl_xor(acc.z,32);
  acc.w += __shfl_xor(acc.w,16); acc.w += __shfl_xor(acc.w,32);
  if (grp == 0)
    *(float4*)(out + (size_t)i*ODIM + 4*p) = acc;
}

extern "C" void kernel_launch(void* const* d_in, const int* in_sizes, int n_in,
                              void* d_out, int out_size, void* d_ws, size_t ws_size,
                              hipStream_t stream) {
  const float* x   = (const float*)d_in[0];
  // d_in[1] = batch (unused: sorted equal-size graphs)
  const float* W1  = (const float*)d_in[2];
  const float* b1  = (const float*)d_in[3];
  const float* g1  = (const float*)d_in[4];
  const float* be1 = (const float*)d_in[5];
  const float* Wg  = (const float*)d_in[6];
  const float* bg  = (const float*)d_in[7];
  const float* gg  = (const float*)d_in[8];
  const float* beg = (const float*)d_in[9];
  float* out = (float*)d_out;

  char* ws = (char*)d_ws;
  int*   idx   = (int*)  (ws);                         // 2 MB
  float* P     = (float*)(ws + 2097152);               // 8 MB
  float* Q     = (float*)(ws + 10485760);              // 8 MB
  float* sq    = (float*)(ws + 18874368);              // 128 KB
  float* pbuf  = (float*)(ws + 19005440);              // 1 MB   [128][2048]
  float* gpart = (float*)(ws + 20054016);              // 16 KB  [2048][2]
  float* gtbuf = (float*)(ws + 20070400);              // 2 MB   [NEDGE]
  float* scale = (float*)(ws + 22167552);              // 64 f
  float* shift = (float*)(ws + 22167808);              // 64 f
  float* gsc   = (float*)(ws + 22168064);              // 2 f
  int*   cnts  = (int*)  (ws + 22168072);              // 2 ints (last-block ctrs)

  pq_kernel<<<NTOT/4, 256, 0, stream>>>(x, W1, b1, P, Q, sq, cnts);
  knn_kernel<<<NTOT/KROWS, 256, 0, stream>>>(x, sq, idx);
  stats1f_kernel<<<NBLK_E, 256, 0, stream>>>(P, Q, idx, g1, be1, pbuf, scale, shift, &cnts[0]);
  stats2f_kernel<<<NBLK_E, 256, 0, stream>>>(P, Q, idx, scale, shift, Wg, bg, gg, beg, gtbuf, gpart, gsc, &cnts[1]);
  final_kernel<<<NTOT/4, 256, 0, stream>>>(P, Q, idx, scale, shift, gtbuf, gsc, out);
}

// Round 12
// 277.870 us; speedup vs baseline: 2.6819x; 2.6819x over previous
//
#include <hip/hip_runtime.h>
#include <math.h>
#include <float.h>

#define BGRAPH 16
#define NPTS   2048
#define CDIM   16
#define ODIM   64
#define KNN    16
#define NTOT   (BGRAPH*NPTS)     // 32768
#define NEDGE  (NTOT*KNN)        // 524288
#define EPSBN  1e-5f
#define NBLK_E 2048              // blocks for edge-stat passes
#define NPW    4                 // nodes per wave in edge-stat passes
#define NSETS  16                // accumulator stripes (contention vs reduce size)

// SYNC LESSONS (r10/r11, measured):
//  - cooperative grid.sync(): ~100us per sync (4 syncs = +430us). NO.
//  - per-block __threadfence(): L2 writeback/invalidate per fence on gfx950
//    (non-coherent per-XCD L2s); 2048 blocks = +250us stall. NO.
//  - kernel boundary: ~10us, and it IS a full device sync. Use atomicAdd
//    (device-scope by default) to accumulate partials; consume them in the
//    NEXT dispatch. No fences, no waits.

// ---------------- P = x@W1b, Q = x@(W1a-W1b)+b1, sq = rowsum(x*x) ----------
// Block 0 also zeroes the striped accumulators (abuf 16x128 + gacc 32),
// re-zeroed on every launch (graph replay safe); runs strictly before stats.
__global__ __launch_bounds__(256) void pq_kernel(
    const float* __restrict__ x, const float* __restrict__ W1,
    const float* __restrict__ b1,
    float* __restrict__ P, float* __restrict__ Q, float* __restrict__ sq,
    float* __restrict__ abuf) {
  if (blockIdx.x == 0) {
    for (int t = threadIdx.x; t < NSETS*128 + 2*NSETS; t += 256) abuf[t] = 0.f;
  }
  int lane = threadIdx.x & 63;
  int nin  = threadIdx.x >> 6;           // node within block (0..3)
  int node = blockIdx.x * 4 + nin;
  __shared__ float xs[4][CDIM];
  if (threadIdx.x < 4*CDIM) {
    int n = threadIdx.x / CDIM, c = threadIdx.x % CDIM;
    xs[n][c] = x[(blockIdx.x*4 + n)*CDIM + c];
  }
  __syncthreads();
  float p = 0.f, q = b1[lane];
  #pragma unroll
  for (int c = 0; c < CDIM; ++c) {
    float xv = xs[nin][c];
    float wb = W1[(c+CDIM)*ODIM + lane];
    float wa = W1[c*ODIM + lane];
    p += xv * wb;
    q += xv * (wa - wb);
  }
  P[node*ODIM + lane] = p;
  Q[node*ODIM + lane] = q;
  if (lane == 0) {
    float s = 0.f;
    #pragma unroll
    for (int c = 0; c < CDIM; ++c) { float xv = xs[nin][c]; s += xv*xv; }
    sq[node] = s;
  }
}

// ---------------- kNN: one row per wave, all state in registers -------------
// FROZEN round-1 kernel (measured r6/r9: ~114us, VGPR=60, WRITE=2MB). Every
// R=2 attempt (r2-r5) put the distance array in scratch (2GB WRITE, 7-11x
// slower). Flat d[32] + ~56 VGPR demand is the proven-promotable shape on
// this compiler. Do not increase per-thread state here.
#define KROWS 4
__device__ __forceinline__ unsigned long long packkey(float dv, int j) {
  unsigned ub = __float_as_uint(dv);
  ub ^= ((unsigned)((int)ub >> 31)) | 0x80000000u;   // monotone f32->u32
  return (((unsigned long long)ub) << 32) | (unsigned)j;
}

__global__ __launch_bounds__(256, 4) void knn_kernel(
    const float* __restrict__ x, const float* __restrict__ sq,
    int* __restrict__ idxOut) {
  __shared__ float sT16[CDIM][256];                 // transposed tile, 16 KB
  __shared__ unsigned long long skey[4][64];        // per-wave survivor keys
  __shared__ int scnt[4];
  const int tid  = threadIdx.x;
  const int lane = tid & 63;
  const int w    = tid >> 6;
  const int blocksPerGraph = NPTS / KROWS;          // 512
  const int g     = blockIdx.x / blocksPerGraph;
  const int rb    = (blockIdx.x % blocksPerGraph) * KROWS;
  const int gbase = g * NPTS;
  const int r0    = rb + w;                         // this wave's single row

  float tg[CDIM]; float tsq;
  {
    const float4* tp = (const float4*)(x + (size_t)(gbase + r0)*CDIM);
    float4 t0 = tp[0], t1 = tp[1], t2 = tp[2], t3 = tp[3];
    tg[0]=t0.x; tg[1]=t0.y; tg[2]=t0.z; tg[3]=t0.w;
    tg[4]=t1.x; tg[5]=t1.y; tg[6]=t1.z; tg[7]=t1.w;
    tg[8]=t2.x; tg[9]=t2.y; tg[10]=t2.z; tg[11]=t2.w;
    tg[12]=t3.x; tg[13]=t3.y; tg[14]=t3.z; tg[15]=t3.w;
    tsq = sq[gbase + r0];
  }

  float d[32];

  // prefetch tile 0 into regs
  float4 a0, a1, a2, a3;
  {
    const float4* xp = (const float4*)(x + (size_t)(gbase + tid)*CDIM);
    a0 = xp[0]; a1 = xp[1]; a2 = xp[2]; a3 = xp[3];
  }

  for (int t = 0; t < NPTS/256; ++t) {
    __syncthreads();                                // prev tile reads done
    sT16[0][tid]=a0.x;  sT16[1][tid]=a0.y;  sT16[2][tid]=a0.z;  sT16[3][tid]=a0.w;
    sT16[4][tid]=a1.x;  sT16[5][tid]=a1.y;  sT16[6][tid]=a1.z;  sT16[7][tid]=a1.w;
    sT16[8][tid]=a2.x;  sT16[9][tid]=a2.y;  sT16[10][tid]=a2.z; sT16[11][tid]=a2.w;
    sT16[12][tid]=a3.x; sT16[13][tid]=a3.y; sT16[14][tid]=a3.z; sT16[15][tid]=a3.w;
    __syncthreads();
    if (t < NPTS/256 - 1) {                         // issue next-tile loads early
      const float4* xp = (const float4*)(x + (size_t)(gbase + (t+1)*256 + tid)*CDIM);
      a0 = xp[0]; a1 = xp[1]; a2 = xp[2]; a3 = xp[3];
    }

    float4 sq4 = *(const float4*)(sq + gbase + t*256 + 4*lane);
    float sqv[4] = {sq4.x, sq4.y, sq4.z, sq4.w};

    float dot[4] = {0.f,0.f,0.f,0.f};
    #pragma unroll
    for (int c = 0; c < CDIM; ++c) {
      float4 cv = *(const float4*)(&sT16[c][4*lane]);
      float cvv[4]; cvv[0]=cv.x; cvv[1]=cv.y; cvv[2]=cv.z; cvv[3]=cv.w;
      float xv = tg[c];
      #pragma unroll
      for (int rr = 0; rr < 4; ++rr)
        dot[rr] += xv * cvv[rr];
    }
    #pragma unroll
    for (int rr = 0; rr < 4; ++rr)
      d[t*4 + rr] = tsq + sqv[rr] - 2.f*dot[rr];
  }

  {
    float lmin = d[0];
    #pragma unroll
    for (int s = 1; s < 32; ++s) lmin = fminf(lmin, d[s]);

    float v = lmin;
    #pragma unroll
    for (int k = 2; k <= 64; k <<= 1) {
      #pragma unroll
      for (int j = k >> 1; j > 0; j >>= 1) {
        float o = __shfl_xor(v, j);
        bool asc   = ((lane & k) == 0);
        bool lower = ((lane & j) == 0);
        float mn = fminf(v, o), mx = fmaxf(v, o);
        v = (asc == lower) ? mn : mx;
      }
    }
    float T = __shfl(v, 15);

    if (lane == 0) scnt[w] = 0;
    #pragma unroll
    for (int s = 0; s < 32; ++s) {
      if (d[s] <= T) {
        int p = atomicAdd(&scnt[w], 1);
        if (p < 64) {
          int j = (s >> 2)*256 + 4*lane + (s & 3);
          skey[w][p] = packkey(d[s], j);
        }
      }
    }
    int M = scnt[w];
    int row = gbase + r0;

    if (M <= 64) {
      unsigned long long key = (lane < M) ? skey[w][lane] : ~0ull;
      #pragma unroll
      for (int k = 2; k <= 64; k <<= 1) {
        #pragma unroll
        for (int j = k >> 1; j > 0; j >>= 1) {
          unsigned long long o = __shfl_xor(key, j);
          bool asc   = ((lane & k) == 0);
          bool lower = ((lane & j) == 0);
          unsigned long long mn = (key < o) ? key : o;
          unsigned long long mx = (key < o) ? o : key;
          key = (asc == lower) ? mn : mx;
        }
      }
      if (lane < KNN)
        idxOut[(size_t)row*KNN + lane] = gbase + (int)(key & 0xffffffffu);
    } else {
      for (int sel = 0; sel < KNN; ++sel) {
        unsigned long long lb = ~0ull;
        #pragma unroll
        for (int s = 0; s < 32; ++s) {
          int j = (s >> 2)*256 + 4*lane + (s & 3);
          unsigned long long ks = packkey(d[s], j);
          if (ks < lb) lb = ks;
        }
        #pragma unroll
        for (int off = 32; off > 0; off >>= 1) {
          unsigned long long o = __shfl_xor(lb, off);
          if (o < lb) lb = o;
        }
        if (lane == 0)
          idxOut[(size_t)row*KNN + sel] = gbase + (int)(lb & 0xffffffffu);
        #pragma unroll
        for (int s = 0; s < 32; ++s) {
          int j = (s >> 2)*256 + 4*lane + (s & 3);
          if (packkey(d[s], j) == lb) d[s] = FLT_MAX;
        }
      }
    }
  }
}

// ---------------- stats pass 1 (grouped) + striped-atomic accumulate --------
// Body = r9-verified grouped stats1. Tail: tid<128 does ONE atomicAdd into
// abuf[(blk%16)*128 + tid] (rows 0..63 = sum, 64..127 = sumsq). 128 adds per
// address, staggered by block completion -> hidden. No fence needed: consumer
// is the next dispatch (kernel boundary = device sync).
__global__ __launch_bounds__(256) void stats1a_kernel(
    const float* __restrict__ P, const float* __restrict__ Q,
    const int* __restrict__ idx, float* __restrict__ abuf) {
  int tid  = threadIdx.x;
  int lane = tid & 63;
  int wid  = tid >> 6;
  int grp  = lane >> 4;                 // edge-quad slot 0..3
  int p    = lane & 15;                 // channel quad 0..15
  int gw   = blockIdx.x * 4 + wid;
  int n0 = gw * NPW;
  float4 s4  = {0.f,0.f,0.f,0.f};
  float4 ss4 = {0.f,0.f,0.f,0.f};
  #pragma unroll
  for (int ii = 0; ii < NPW; ++ii) {
    int i = n0 + ii;
    float4 q4 = *(const float4*)(Q + (size_t)i*ODIM + 4*p);
    int4 j4 = *(const int4*)(idx + (size_t)i*KNN + 4*grp);
    {
      float4 v = *(const float4*)(P + (size_t)j4.x*ODIM + 4*p);
      float hx=q4.x+v.x, hy=q4.y+v.y, hz=q4.z+v.z, hw=q4.w+v.w;
      s4.x+=hx; s4.y+=hy; s4.z+=hz; s4.w+=hw;
      ss4.x+=hx*hx; ss4.y+=hy*hy; ss4.z+=hz*hz; ss4.w+=hw*hw;
    }
    {
      float4 v = *(const float4*)(P + (size_t)j4.y*ODIM + 4*p);
      float hx=q4.x+v.x, hy=q4.y+v.y, hz=q4.z+v.z, hw=q4.w+v.w;
      s4.x+=hx; s4.y+=hy; s4.z+=hz; s4.w+=hw;
      ss4.x+=hx*hx; ss4.y+=hy*hy; ss4.z+=hz*hz; ss4.w+=hw*hw;
    }
    {
      float4 v = *(const float4*)(P + (size_t)j4.z*ODIM + 4*p);
      float hx=q4.x+v.x, hy=q4.y+v.y, hz=q4.z+v.z, hw=q4.w+v.w;
      s4.x+=hx; s4.y+=hy; s4.z+=hz; s4.w+=hw;
      ss4.x+=hx*hx; ss4.y+=hy*hy; ss4.z+=hz*hz; ss4.w+=hw*hw;
    }
    {
      float4 v = *(const float4*)(P + (size_t)j4.w*ODIM + 4*p);
      float hx=q4.x+v.x, hy=q4.y+v.y, hz=q4.z+v.z, hw=q4.w+v.w;
      s4.x+=hx; s4.y+=hy; s4.z+=hz; s4.w+=hw;
      ss4.x+=hx*hx; ss4.y+=hy*hy; ss4.z+=hz*hz; ss4.w+=hw*hw;
    }
  }
  // cross-group reduce (each group's partial enters ONCE; xor16/32 cross
  // group boundaries only — r7 post-mortem)
  s4.x  += __shfl_xor(s4.x,16);  s4.x  += __shfl_xor(s4.x,32);
  s4.y  += __shfl_xor(s4.y,16);  s4.y  += __shfl_xor(s4.y,32);
  s4.z  += __shfl_xor(s4.z,16);  s4.z  += __shfl_xor(s4.z,32);
  s4.w  += __shfl_xor(s4.w,16);  s4.w  += __shfl_xor(s4.w,32);
  ss4.x += __shfl_xor(ss4.x,16); ss4.x += __shfl_xor(ss4.x,32);
  ss4.y += __shfl_xor(ss4.y,16); ss4.y += __shfl_xor(ss4.y,32);
  ss4.z += __shfl_xor(ss4.z,16); ss4.z += __shfl_xor(ss4.z,32);
  ss4.w += __shfl_xor(ss4.w,16); ss4.w += __shfl_xor(ss4.w,32);
  __shared__ float ls[4][ODIM], lss[4][ODIM];
  if (grp == 0) {
    *(float4*)&ls[wid][4*p]  = s4;
    *(float4*)&lss[wid][4*p] = ss4;
  }
  __syncthreads();
  if (tid < 2*ODIM) {
    float a;
    if (tid < ODIM) a = ls[0][tid] + ls[1][tid] + ls[2][tid] + ls[3][tid];
    else { int o = tid - ODIM; a = lss[0][o] + lss[1][o] + lss[2][o] + lss[3][o]; }
    atomicAdd(&abuf[(blockIdx.x & (NSETS-1))*128 + tid], a);
  }
}

// ---------------- stats pass 2: BN prologue + gate + striped-atomic tail ----
// Prologue: every block reduces abuf (16x128) -> scale/shift in shared
// (~0.3us, overlapped). Block 0 publishes to global for final. Body =
// r9-verified grouped gate pass. Tail: 2 atomicAdds into gacc stripe.
__global__ __launch_bounds__(256) void stats2a_kernel(
    const float* __restrict__ P, const float* __restrict__ Q,
    const int* __restrict__ idx,
    const float* __restrict__ g1, const float* __restrict__ be1,
    const float* __restrict__ Wg, const float* __restrict__ bg,
    const float* __restrict__ abuf, float* __restrict__ scale,
    float* __restrict__ shift, float* __restrict__ gtbuf,
    float* __restrict__ gacc) {
  int tid  = threadIdx.x;
  int lane = tid & 63;
  int wid  = tid >> 6;
  int grp  = lane >> 4;                 // edge-quad slot
  int p    = lane & 15;                 // channel quad
  __shared__ __align__(16) float s_sc[ODIM], s_sh[ODIM];
  __shared__ float red[2*ODIM];
  if (tid < 2*ODIM) {
    float a = 0.f;
    #pragma unroll
    for (int t = 0; t < NSETS; ++t) a += abuf[t*128 + tid];   // deterministic order
    red[tid] = a;
  }
  __syncthreads();
  if (tid < ODIM) {
    float mu  = red[tid] / (float)NEDGE;
    float var = red[ODIM+tid] / (float)NEDGE - mu*mu;
    float inv = 1.0f / sqrtf(var + EPSBN);
    float sc = g1[tid] * inv;
    float sh = be1[tid] - mu * sc;
    s_sc[tid] = sc; s_sh[tid] = sh;
    if (blockIdx.x == 0) { scale[tid] = sc; shift[tid] = sh; }  // for final
  }
  __syncthreads();

  int gw = blockIdx.x * 4 + wid;
  int n0 = gw * NPW;
  float4 sc4 = *(const float4*)&s_sc[4*p];
  float4 sh4 = *(const float4*)&s_sh[4*p];
  float4 wg4 = *(const float4*)(Wg + 4*p);
  float bgv = bg[0];
  float s = 0.f, ss = 0.f;
  #pragma unroll
  for (int ii = 0; ii < NPW; ++ii) {
    int i = n0 + ii;
    float4 q4 = *(const float4*)(Q + (size_t)i*ODIM + 4*p);
    int4 j4 = *(const int4*)(idx + (size_t)i*KNN + 4*grp);
    #pragma unroll
    for (int e = 0; e < 4; ++e) {
      int j = (e==0) ? j4.x : (e==1) ? j4.y : (e==2) ? j4.z : j4.w;
      float4 p4 = *(const float4*)(P + (size_t)j*ODIM + 4*p);
      float zx = (q4.x + p4.x)*sc4.x + sh4.x;
      float zy = (q4.y + p4.y)*sc4.y + sh4.y;
      float zz = (q4.z + p4.z)*sc4.z + sh4.z;
      float zw = (q4.w + p4.w)*sc4.w + sh4.w;
      float v = (zx/(1.f+expf(-zx)))*wg4.x
              + (zy/(1.f+expf(-zy)))*wg4.y
              + (zz/(1.f+expf(-zz)))*wg4.z
              + (zw/(1.f+expf(-zw)))*wg4.w;
      v += __shfl_xor(v, 1);
      v += __shfl_xor(v, 2);
      v += __shfl_xor(v, 4);
      v += __shfl_xor(v, 8);            // group-wide sum over 64 channels
      float gt = v + bgv;
      if (p == 0) gtbuf[(size_t)i*KNN + 4*grp + e] = gt;
      s += gt; ss += gt*gt;             // per-group partial
    }
  }
  // each group's total enters exactly once (xor16/32 cross groups only)
  s  += __shfl_xor(s, 16);  s  += __shfl_xor(s, 32);
  ss += __shfl_xor(ss, 16); ss += __shfl_xor(ss, 32);
  __shared__ float pw[4], pws[4];
  if (lane == 0) { pw[wid] = s; pws[wid] = ss; }
  __syncthreads();
  if (tid == 0) {
    int set = blockIdx.x & (NSETS-1);
    atomicAdd(&gacc[2*set],   pw[0]+pw[1]+pw[2]+pw[3]);
    atomicAdd(&gacc[2*set+1], pws[0]+pws[1]+pws[2]+pws[3]);
  }
}

// ---------------- final: gsc prologue + softmax over K + weighted sum -------
// Prologue: thread 0 reduces gacc (32 floats, L2-resident) -> gate BN
// scale/shift in shared (~0.3us, overlapped). Body = r9-verified grouped
// final.
__global__ __launch_bounds__(256) void final_kernel(
    const float* __restrict__ P, const float* __restrict__ Q,
    const int* __restrict__ idx, const float* __restrict__ scale,
    const float* __restrict__ shift, const float* __restrict__ gtbuf,
    const float* __restrict__ gacc, const float* __restrict__ gg,
    const float* __restrict__ beg, float* __restrict__ out) {
  __shared__ float g2[2];
  if (threadIdx.x == 0) {
    float S = 0.f, SS = 0.f;
    #pragma unroll
    for (int t = 0; t < NSETS; ++t) { S += gacc[2*t]; SS += gacc[2*t+1]; }
    float mu  = S / (float)NEDGE;
    float var = SS / (float)NEDGE - mu*mu;
    float inv = 1.f / sqrtf(var + EPSBN);
    float sg = gg[0] * inv;
    g2[0] = sg; g2[1] = beg[0] - mu * sg;
  }
  __syncthreads();
  int lane = threadIdx.x & 63;
  int wid  = threadIdx.x >> 6;
  int grp  = lane >> 4;
  int p    = lane & 15;
  int i = blockIdx.x * 4 + wid;
  float4 sc4 = *(const float4*)(scale + 4*p);
  float4 sh4 = *(const float4*)(shift + 4*p);
  float gscale = g2[0], gshift = g2[1];
  float4 q4 = *(const float4*)(Q + (size_t)i*ODIM + 4*p);
  int4   j4 = *(const int4*)(idx + (size_t)i*KNN + 4*grp);
  float4 g4 = *(const float4*)(gtbuf + (size_t)i*KNN + 4*grp);

  float z0 = g4.x*gscale + gshift, z1 = g4.y*gscale + gshift;
  float z2 = g4.z*gscale + gshift, z3 = g4.w*gscale + gshift;
  float gt0 = z0/(1.f+expf(-z0)), gt1 = z1/(1.f+expf(-z1));
  float gt2 = z2/(1.f+expf(-z2)), gt3 = z3/(1.f+expf(-z3));
  float m = fmaxf(fmaxf(gt0, gt1), fmaxf(gt2, gt3));
  m = fmaxf(m, __shfl_xor(m, 16));
  m = fmaxf(m, __shfl_xor(m, 32));
  float e0 = expf(gt0-m), e1 = expf(gt1-m), e2 = expf(gt2-m), e3 = expf(gt3-m);
  float se = e0+e1+e2+e3;
  se += __shfl_xor(se, 16);
  se += __shfl_xor(se, 32);
  float invs = 1.f / se;
  float a0 = e0*invs, a1 = e1*invs, a2 = e2*invs, a3 = e3*invs;

  float4 acc = {0.f,0.f,0.f,0.f};
  {
    float4 v = *(const float4*)(P + (size_t)j4.x*ODIM + 4*p);
    float zx=(q4.x+v.x)*sc4.x+sh4.x, zy=(q4.y+v.y)*sc4.y+sh4.y;
    float zz=(q4.z+v.z)*sc4.z+sh4.z, zw=(q4.w+v.w)*sc4.w+sh4.w;
    acc.x += a0*(zx/(1.f+expf(-zx))); acc.y += a0*(zy/(1.f+expf(-zy)));
    acc.z += a0*(zz/(1.f+expf(-zz))); acc.w += a0*(zw/(1.f+expf(-zw)));
  }
  {
    float4 v = *(const float4*)(P + (size_t)j4.y*ODIM + 4*p);
    float zx=(q4.x+v.x)*sc4.x+sh4.x, zy=(q4.y+v.y)*sc4.y+sh4.y;
    float zz=(q4.z+v.z)*sc4.z+sh4.z, zw=(q4.w+v.w)*sc4.w+sh4.w;
    acc.x += a1*(zx/(1.f+expf(-zx))); acc.y += a1*(zy/(1.f+expf(-zy)));
    acc.z += a1*(zz/(1.f+expf(-zz))); acc.w += a1*(zw/(1.f+expf(-zw)));
  }
  {
    float4 v = *(const float4*)(P + (size_t)j4.z*ODIM + 4*p);
    float zx=(q4.x+v.x)*sc4.x+sh4.x, zy=(q4.y+v.y)*sc4.y+sh4.y;
    float zz=(q4.z+v.z)*sc4.z+sh4.z, zw=(q4.w+v.w)*sc4.w+sh4.w;
    acc.x += a2*(zx/(1.f+expf(-zx))); acc.y += a2*(zy/(1.f+expf(-zy)));
    acc.z += a2*(zz/(1.f+expf(-zz))); acc.w += a2*(zw/(1.f+expf(-zw)));
  }
  {
    float4 v = *(const float4*)(P + (size_t)j4.w*ODIM + 4*p);
    float zx=(q4.x+v.x)*sc4.x+sh4.x, zy=(q4.y+v.y)*sc4.y+sh4.y;
    float zz=(q4.z+v.z)*sc4.z+sh4.z, zw=(q4.w+v.w)*sc4.w+sh4.w;
    acc.x += a3*(zx/(1.f+expf(-zx))); acc.y += a3*(zy/(1.f+expf(-zy)));
    acc.z += a3*(zz/(1.f+expf(-zz))); acc.w += a3*(zw/(1.f+expf(-zw)));
  }
  acc.x += __shfl_xor(acc.x,16); acc.x += __shfl_xor(acc.x,32);
  acc.y += __shfl_xor(acc.y,16); acc.y += __shfl_xor(acc.y,32);
  acc.z += __shfl_xor(acc.z,16); acc.z += __shfl_xor(acc.z,32);
  acc.w += __shfl_xor(acc.w,16); acc.w += __shfl_xor(acc.w,32);
  if (grp == 0)
    *(float4*)(out + (size_t)i*ODIM + 4*p) = acc;
}

extern "C" void kernel_launch(void* const* d_in, const int* in_sizes, int n_in,
                              void* d_out, int out_size, void* d_ws, size_t ws_size,
                              hipStream_t stream) {
  const float* x   = (const float*)d_in[0];
  // d_in[1] = batch (unused: sorted equal-size graphs)
  const float* W1  = (const float*)d_in[2];
  const float* b1  = (const float*)d_in[3];
  const float* g1  = (const float*)d_in[4];
  const float* be1 = (const float*)d_in[5];
  const float* Wg  = (const float*)d_in[6];
  const float* bg  = (const float*)d_in[7];
  const float* gg  = (const float*)d_in[8];
  const float* beg = (const float*)d_in[9];
  float* out = (float*)d_out;

  char* ws = (char*)d_ws;
  int*   idx   = (int*)  (ws);                         // 2 MB
  float* P     = (float*)(ws + 2097152);               // 8 MB
  float* Q     = (float*)(ws + 10485760);              // 8 MB
  float* sq    = (float*)(ws + 18874368);              // 128 KB
  float* abuf  = (float*)(ws + 19005440);              // 16x128 f + 32 f (in old pbuf region)
  float* gacc  = abuf + NSETS*128;                     // 32 f
  float* gtbuf = (float*)(ws + 20070400);              // 2 MB   [NEDGE]
  float* scale = (float*)(ws + 22167552);              // 64 f
  float* shift = (float*)(ws + 22167808);              // 64 f

  pq_kernel<<<NTOT/4, 256, 0, stream>>>(x, W1, b1, P, Q, sq, abuf);
  knn_kernel<<<NTOT/KROWS, 256, 0, stream>>>(x, sq, idx);
  stats1a_kernel<<<NBLK_E, 256, 0, stream>>>(P, Q, idx, abuf);
  stats2a_kernel<<<NBLK_E, 256, 0, stream>>>(P, Q, idx, g1, be1, Wg, bg, abuf, scale, shift, gtbuf, gacc);
  final_kernel<<<NTOT/4, 256, 0, stream>>>(P, Q, idx, scale, shift, gtbuf, gacc, gg, beg, out);
}

// Round 13
// 276.904 us; speedup vs baseline: 2.6912x; 1.0035x over previous
//
#include <hip/hip_runtime.h>
#include <math.h>
#include <float.h>

#define BGRAPH 16
#define NPTS   2048
#define CDIM   16
#define ODIM   64
#define KNN    16
#define NTOT   (BGRAPH*NPTS)     // 32768
#define NEDGE  (NTOT*KNN)        // 524288
#define EPSBN  1e-5f
#define NBLK_E 2048              // blocks for edge-stat passes
#define NPW    4                 // nodes per wave in edge-stat passes
#define NSETS  16                // accumulator stripes

// SYNC LESSONS (r10/r11/r12, measured):
//  - cooperative grid.sync(): ~100us per sync. NO.
//  - per-block __threadfence(): ~250us total (L2 writeback per fence). NO.
//  - kernel boundary: ~0.4us (r12: removing 2 dispatches saved ~1us total).
//    Striped atomicAdd partials consumed by the next dispatch = free sync.

// ---------------- P = x@W1b, Q = x@(W1a-W1b)+b1, sq = rowsum(x*x) ----------
// Block 0 also zeroes the striped accumulators (graph-replay safe).
__global__ __launch_bounds__(256) void pq_kernel(
    const float* __restrict__ x, const float* __restrict__ W1,
    const float* __restrict__ b1,
    float* __restrict__ P, float* __restrict__ Q, float* __restrict__ sq,
    float* __restrict__ abuf) {
  if (blockIdx.x == 0) {
    for (int t = threadIdx.x; t < NSETS*128 + 2*NSETS; t += 256) abuf[t] = 0.f;
  }
  int lane = threadIdx.x & 63;
  int nin  = threadIdx.x >> 6;           // node within block (0..3)
  int node = blockIdx.x * 4 + nin;
  __shared__ float xs[4][CDIM];
  if (threadIdx.x < 4*CDIM) {
    int n = threadIdx.x / CDIM, c = threadIdx.x % CDIM;
    xs[n][c] = x[(blockIdx.x*4 + n)*CDIM + c];
  }
  __syncthreads();
  float p = 0.f, q = b1[lane];
  #pragma unroll
  for (int c = 0; c < CDIM; ++c) {
    float xv = xs[nin][c];
    float wb = W1[(c+CDIM)*ODIM + lane];
    float wa = W1[c*ODIM + lane];
    p += xv * wb;
    q += xv * (wa - wb);
  }
  P[node*ODIM + lane] = p;
  Q[node*ODIM + lane] = q;
  if (lane == 0) {
    float s = 0.f;
    #pragma unroll
    for (int c = 0; c < CDIM; ++c) { float xv = xs[nin][c]; s += xv*xv; }
    sq[node] = s;
  }
}

// ---------------- kNN: hybrid 2 rows/wave — row A in regs, row B in LDS ----
// LDS-pipe bound: cv tile-reads (~1536 cyc/wave) are shared by BOTH rows, so
// rows/wave divides the dominant cost. r2-r5 spilled because per-thread REG
// demand hit ~130 (allocator targets 84 and dumps to scratch). This keeps
// demand BELOW the proven r1 shape: row A = flat d[32] regs (r1-exact), row
// B's 32 distances live in LDS dB[s][tid] (per-thread column, bank=tid%32,
// 2 lanes/bank = conflict-free, zero sync). Row feats -> SGPRs via
// readfirstlane (r3-r5 proven correct). LDS 51KB -> 3 blocks/CU (12 waves).
// REVERT RULE: WRITE_SIZE>10MB or dur>115us -> restore r12 knn, knn is floor.
#define KROWS 8
__device__ __forceinline__ unsigned long long packkey(float dv, int j) {
  unsigned ub = __float_as_uint(dv);
  ub ^= ((unsigned)((int)ub >> 31)) | 0x80000000u;   // monotone f32->u32
  return (((unsigned long long)ub) << 32) | (unsigned)j;
}
__device__ __forceinline__ float rfl(float v) {
  return __uint_as_float(__builtin_amdgcn_readfirstlane(__float_as_uint(v)));
}

__global__ __launch_bounds__(256, 3) void knn_kernel(
    const float* __restrict__ x, const float* __restrict__ sq,
    int* __restrict__ idxOut) {
  __shared__ float sT16[CDIM][256];                 // transposed tile, 16 KB
  __shared__ float dB[32][256];                     // row-B dists, 32 KB
  __shared__ unsigned long long skey[4][64];        // per-wave survivor keys
  __shared__ int scnt[4];
  const int tid  = threadIdx.x;
  const int lane = tid & 63;
  const int w    = tid >> 6;
  const int blocksPerGraph = NPTS / KROWS;          // 256
  const int g     = blockIdx.x / blocksPerGraph;
  const int rb    = (blockIdx.x % blocksPerGraph) * KROWS;
  const int gbase = g * NPTS;
  const int r0    = rb + w*2;                       // rows r0 (A), r0+1 (B)

  // wave-uniform row features -> SGPRs
  float ta[CDIM], tb[CDIM]; float tsqA, tsqB;
  {
    const float4* tp = (const float4*)(x + (size_t)(gbase + r0)*CDIM);
    float4 t0 = tp[0], t1 = tp[1], t2 = tp[2], t3 = tp[3];
    ta[0]=rfl(t0.x);  ta[1]=rfl(t0.y);  ta[2]=rfl(t0.z);  ta[3]=rfl(t0.w);
    ta[4]=rfl(t1.x);  ta[5]=rfl(t1.y);  ta[6]=rfl(t1.z);  ta[7]=rfl(t1.w);
    ta[8]=rfl(t2.x);  ta[9]=rfl(t2.y);  ta[10]=rfl(t2.z); ta[11]=rfl(t2.w);
    ta[12]=rfl(t3.x); ta[13]=rfl(t3.y); ta[14]=rfl(t3.z); ta[15]=rfl(t3.w);
    tsqA = rfl(sq[gbase + r0]);
    const float4* up = (const float4*)(x + (size_t)(gbase + r0 + 1)*CDIM);
    float4 u0 = up[0], u1 = up[1], u2 = up[2], u3 = up[3];
    tb[0]=rfl(u0.x);  tb[1]=rfl(u0.y);  tb[2]=rfl(u0.z);  tb[3]=rfl(u0.w);
    tb[4]=rfl(u1.x);  tb[5]=rfl(u1.y);  tb[6]=rfl(u1.z);  tb[7]=rfl(u1.w);
    tb[8]=rfl(u2.x);  tb[9]=rfl(u2.y);  tb[10]=rfl(u2.z); tb[11]=rfl(u2.w);
    tb[12]=rfl(u3.x); tb[13]=rfl(u3.y); tb[14]=rfl(u3.z); tb[15]=rfl(u3.w);
    tsqB = rfl(sq[gbase + r0 + 1]);
  }

  float d[32];                                      // row A only (r1 shape)

  // prefetch tile 0 into regs (r1-proven staging structure)
  float4 a0, a1, a2, a3;
  {
    const float4* xp = (const float4*)(x + (size_t)(gbase + tid)*CDIM);
    a0 = xp[0]; a1 = xp[1]; a2 = xp[2]; a3 = xp[3];
  }

  #pragma unroll
  for (int t = 0; t < NPTS/256; ++t) {
    __syncthreads();                                // prev tile reads done
    sT16[0][tid]=a0.x;  sT16[1][tid]=a0.y;  sT16[2][tid]=a0.z;  sT16[3][tid]=a0.w;
    sT16[4][tid]=a1.x;  sT16[5][tid]=a1.y;  sT16[6][tid]=a1.z;  sT16[7][tid]=a1.w;
    sT16[8][tid]=a2.x;  sT16[9][tid]=a2.y;  sT16[10][tid]=a2.z; sT16[11][tid]=a2.w;
    sT16[12][tid]=a3.x; sT16[13][tid]=a3.y; sT16[14][tid]=a3.z; sT16[15][tid]=a3.w;
    __syncthreads();
    if (t < NPTS/256 - 1) {                         // issue next-tile loads early
      const float4* xp = (const float4*)(x + (size_t)(gbase + (t+1)*256 + tid)*CDIM);
      a0 = xp[0]; a1 = xp[1]; a2 = xp[2]; a3 = xp[3];
    }

    float4 sq4 = *(const float4*)(sq + gbase + t*256 + 4*lane);
    float sqv[4] = {sq4.x, sq4.y, sq4.z, sq4.w};

    float dotA[4] = {0.f,0.f,0.f,0.f};
    float dotB[4] = {0.f,0.f,0.f,0.f};
    #pragma unroll
    for (int c = 0; c < CDIM; ++c) {
      float4 cv = *(const float4*)(&sT16[c][4*lane]);   // shared by both rows
      float xa = ta[c], xb = tb[c];                 // SGPR operands
      dotA[0] += xa*cv.x; dotA[1] += xa*cv.y; dotA[2] += xa*cv.z; dotA[3] += xa*cv.w;
      dotB[0] += xb*cv.x; dotB[1] += xb*cv.y; dotB[2] += xb*cv.z; dotB[3] += xb*cv.w;
    }
    #pragma unroll
    for (int rr = 0; rr < 4; ++rr) {
      d[t*4 + rr] = tsqA + sqv[rr] - 2.f*dotA[rr];          // regs (row A)
      dB[t*4 + rr][tid] = tsqB + sqv[rr] - 2.f*dotB[rr];    // LDS  (row B)
    }
  }

  // -------- SELECT row A (registers — r1-proven body) --------
  {
    float lmin = d[0];
    #pragma unroll
    for (int s = 1; s < 32; ++s) lmin = fminf(lmin, d[s]);

    float v = lmin;
    #pragma unroll
    for (int k = 2; k <= 64; k <<= 1) {
      #pragma unroll
      for (int j = k >> 1; j > 0; j >>= 1) {
        float o = __shfl_xor(v, j);
        bool asc   = ((lane & k) == 0);
        bool lower = ((lane & j) == 0);
        float mn = fminf(v, o), mx = fmaxf(v, o);
        v = (asc == lower) ? mn : mx;
      }
    }
    float T = __shfl(v, 15);

    if (lane == 0) scnt[w] = 0;
    #pragma unroll
    for (int s = 0; s < 32; ++s) {
      if (d[s] <= T) {
        int p = atomicAdd(&scnt[w], 1);
        if (p < 64) {
          int j = (s >> 2)*256 + 4*lane + (s & 3);
          skey[w][p] = packkey(d[s], j);
        }
      }
    }
    int M = scnt[w];
    int row = gbase + r0;

    if (M <= 64) {
      unsigned long long key = (lane < M) ? skey[w][lane] : ~0ull;
      #pragma unroll
      for (int k = 2; k <= 64; k <<= 1) {
        #pragma unroll
        for (int j = k >> 1; j > 0; j >>= 1) {
          unsigned long long o = __shfl_xor(key, j);
          bool asc   = ((lane & k) == 0);
          bool lower = ((lane & j) == 0);
          unsigned long long mn = (key < o) ? key : o;
          unsigned long long mx = (key < o) ? o : key;
          key = (asc == lower) ? mn : mx;
        }
      }
      if (lane < KNN)
        idxOut[(size_t)row*KNN + lane] = gbase + (int)(key & 0xffffffffu);
    } else {
      for (int sel = 0; sel < KNN; ++sel) {
        unsigned long long lb = ~0ull;
        #pragma unroll
        for (int s = 0; s < 32; ++s) {
          int j = (s >> 2)*256 + 4*lane + (s & 3);
          unsigned long long ks = packkey(d[s], j);
          if (ks < lb) lb = ks;
        }
        #pragma unroll
        for (int off = 32; off > 0; off >>= 1) {
          unsigned long long o = __shfl_xor(lb, off);
          if (o < lb) lb = o;
        }
        if (lane == 0)
          idxOut[(size_t)row*KNN + sel] = gbase + (int)(lb & 0xffffffffu);
        #pragma unroll
        for (int s = 0; s < 32; ++s) {
          int j = (s >> 2)*256 + 4*lane + (s & 3);
          if (packkey(d[s], j) == lb) d[s] = FLT_MAX;
        }
      }
    }
  }

  // -------- SELECT row B (distances in dB[s][tid], same algorithm) --------
  {
    float lmin = dB[0][tid];
    #pragma unroll
    for (int s = 1; s < 32; ++s) lmin = fminf(lmin, dB[s][tid]);

    float v = lmin;
    #pragma unroll
    for (int k = 2; k <= 64; k <<= 1) {
      #pragma unroll
      for (int j = k >> 1; j > 0; j >>= 1) {
        float o = __shfl_xor(v, j);
        bool asc   = ((lane & k) == 0);
        bool lower = ((lane & j) == 0);
        float mn = fminf(v, o), mx = fmaxf(v, o);
        v = (asc == lower) ? mn : mx;
      }
    }
    float T = __shfl(v, 15);

    if (lane == 0) scnt[w] = 0;
    #pragma unroll
    for (int s = 0; s < 32; ++s) {
      float dv = dB[s][tid];
      if (dv <= T) {
        int p = atomicAdd(&scnt[w], 1);
        if (p < 64) {
          int j = (s >> 2)*256 + 4*lane + (s & 3);
          skey[w][p] = packkey(dv, j);
        }
      }
    }
    int M = scnt[w];
    int row = gbase + r0 + 1;

    if (M <= 64) {
      unsigned long long key = (lane < M) ? skey[w][lane] : ~0ull;
      #pragma unroll
      for (int k = 2; k <= 64; k <<= 1) {
        #pragma unroll
        for (int j = k >> 1; j > 0; j >>= 1) {
          unsigned long long o = __shfl_xor(key, j);
          bool asc   = ((lane & k) == 0);
          bool lower = ((lane & j) == 0);
          unsigned long long mn = (key < o) ? key : o;
          unsigned long long mx = (key < o) ? o : key;
          key = (asc == lower) ? mn : mx;
        }
      }
      if (lane < KNN)
        idxOut[(size_t)row*KNN + lane] = gbase + (int)(key & 0xffffffffu);
    } else {
      for (int sel = 0; sel < KNN; ++sel) {
        unsigned long long lb = ~0ull;
        #pragma unroll
        for (int s = 0; s < 32; ++s) {
          int j = (s >> 2)*256 + 4*lane + (s & 3);
          unsigned long long ks = packkey(dB[s][tid], j);
          if (ks < lb) lb = ks;
        }
        #pragma unroll
        for (int off = 32; off > 0; off >>= 1) {
          unsigned long long o = __shfl_xor(lb, off);
          if (o < lb) lb = o;
        }
        if (lane == 0)
          idxOut[(size_t)row*KNN + sel] = gbase + (int)(lb & 0xffffffffu);
        #pragma unroll
        for (int s = 0; s < 32; ++s) {
          int j = (s >> 2)*256 + 4*lane + (s & 3);
          if (packkey(dB[s][tid], j) == lb) dB[s][tid] = FLT_MAX;
        }
      }
    }
  }
}

// ---------------- stats pass 1 (grouped) + striped-atomic accumulate --------
__global__ __launch_bounds__(256) void stats1a_kernel(
    const float* __restrict__ P, const float* __restrict__ Q,
    const int* __restrict__ idx, float* __restrict__ abuf) {
  int tid  = threadIdx.x;
  int lane = tid & 63;
  int wid  = tid >> 6;
  int grp  = lane >> 4;                 // edge-quad slot 0..3
  int p    = lane & 15;                 // channel quad 0..15
  int gw   = blockIdx.x * 4 + wid;
  int n0 = gw * NPW;
  float4 s4  = {0.f,0.f,0.f,0.f};
  float4 ss4 = {0.f,0.f,0.f,0.f};
  #pragma unroll
  for (int ii = 0; ii < NPW; ++ii) {
    int i = n0 + ii;
    float4 q4 = *(const float4*)(Q + (size_t)i*ODIM + 4*p);
    int4 j4 = *(const int4*)(idx + (size_t)i*KNN + 4*grp);
    {
      float4 v = *(const float4*)(P + (size_t)j4.x*ODIM + 4*p);
      float hx=q4.x+v.x, hy=q4.y+v.y, hz=q4.z+v.z, hw=q4.w+v.w;
      s4.x+=hx; s4.y+=hy; s4.z+=hz; s4.w+=hw;
      ss4.x+=hx*hx; ss4.y+=hy*hy; ss4.z+=hz*hz; ss4.w+=hw*hw;
    }
    {
      float4 v = *(const float4*)(P + (size_t)j4.y*ODIM + 4*p);
      float hx=q4.x+v.x, hy=q4.y+v.y, hz=q4.z+v.z, hw=q4.w+v.w;
      s4.x+=hx; s4.y+=hy; s4.z+=hz; s4.w+=hw;
      ss4.x+=hx*hx; ss4.y+=hy*hy; ss4.z+=hz*hz; ss4.w+=hw*hw;
    }
    {
      float4 v = *(const float4*)(P + (size_t)j4.z*ODIM + 4*p);
      float hx=q4.x+v.x, hy=q4.y+v.y, hz=q4.z+v.z, hw=q4.w+v.w;
      s4.x+=hx; s4.y+=hy; s4.z+=hz; s4.w+=hw;
      ss4.x+=hx*hx; ss4.y+=hy*hy; ss4.z+=hz*hz; ss4.w+=hw*hw;
    }
    {
      float4 v = *(const float4*)(P + (size_t)j4.w*ODIM + 4*p);
      float hx=q4.x+v.x, hy=q4.y+v.y, hz=q4.z+v.z, hw=q4.w+v.w;
      s4.x+=hx; s4.y+=hy; s4.z+=hz; s4.w+=hw;
      ss4.x+=hx*hx; ss4.y+=hy*hy; ss4.z+=hz*hz; ss4.w+=hw*hw;
    }
  }
  // cross-group reduce (each group's partial enters ONCE — r7 post-mortem)
  s4.x  += __shfl_xor(s4.x,16);  s4.x  += __shfl_xor(s4.x,32);
  s4.y  += __shfl_xor(s4.y,16);  s4.y  += __shfl_xor(s4.y,32);
  s4.z  += __shfl_xor(s4.z,16);  s4.z  += __shfl_xor(s4.z,32);
  s4.w  += __shfl_xor(s4.w,16);  s4.w  += __shfl_xor(s4.w,32);
  ss4.x += __shfl_xor(ss4.x,16); ss4.x += __shfl_xor(ss4.x,32);
  ss4.y += __shfl_xor(ss4.y,16); ss4.y += __shfl_xor(ss4.y,32);
  ss4.z += __shfl_xor(ss4.z,16); ss4.z += __shfl_xor(ss4.z,32);
  ss4.w += __shfl_xor(ss4.w,16); ss4.w += __shfl_xor(ss4.w,32);
  __shared__ float ls[4][ODIM], lss[4][ODIM];
  if (grp == 0) {
    *(float4*)&ls[wid][4*p]  = s4;
    *(float4*)&lss[wid][4*p] = ss4;
  }
  __syncthreads();
  if (tid < 2*ODIM) {
    float a;
    if (tid < ODIM) a = ls[0][tid] + ls[1][tid] + ls[2][tid] + ls[3][tid];
    else { int o = tid - ODIM; a = lss[0][o] + lss[1][o] + lss[2][o] + lss[3][o]; }
    atomicAdd(&abuf[(blockIdx.x & (NSETS-1))*128 + tid], a);
  }
}

// ---------------- stats pass 2: BN prologue + gate + striped-atomic tail ----
__global__ __launch_bounds__(256) void stats2a_kernel(
    const float* __restrict__ P, const float* __restrict__ Q,
    const int* __restrict__ idx,
    const float* __restrict__ g1, const float* __restrict__ be1,
    const float* __restrict__ Wg, const float* __restrict__ bg,
    const float* __restrict__ abuf, float* __restrict__ scale,
    float* __restrict__ shift, float* __restrict__ gtbuf,
    float* __restrict__ gacc) {
  int tid  = threadIdx.x;
  int lane = tid & 63;
  int wid  = tid >> 6;
  int grp  = lane >> 4;                 // edge-quad slot
  int p    = lane & 15;                 // channel quad
  __shared__ __align__(16) float s_sc[ODIM], s_sh[ODIM];
  __shared__ float red[2*ODIM];
  if (tid < 2*ODIM) {
    float a = 0.f;
    #pragma unroll
    for (int t = 0; t < NSETS; ++t) a += abuf[t*128 + tid];   // deterministic order
    red[tid] = a;
  }
  __syncthreads();
  if (tid < ODIM) {
    float mu  = red[tid] / (float)NEDGE;
    float var = red[ODIM+tid] / (float)NEDGE - mu*mu;
    float inv = 1.0f / sqrtf(var + EPSBN);
    float sc = g1[tid] * inv;
    float sh = be1[tid] - mu * sc;
    s_sc[tid] = sc; s_sh[tid] = sh;
    if (blockIdx.x == 0) { scale[tid] = sc; shift[tid] = sh; }  // for final
  }
  __syncthreads();

  int gw = blockIdx.x * 4 + wid;
  int n0 = gw * NPW;
  float4 sc4 = *(const float4*)&s_sc[4*p];
  float4 sh4 = *(const float4*)&s_sh[4*p];
  float4 wg4 = *(const float4*)(Wg + 4*p);
  float bgv = bg[0];
  float s = 0.f, ss = 0.f;
  #pragma unroll
  for (int ii = 0; ii < NPW; ++ii) {
    int i = n0 + ii;
    float4 q4 = *(const float4*)(Q + (size_t)i*ODIM + 4*p);
    int4 j4 = *(const int4*)(idx + (size_t)i*KNN + 4*grp);
    #pragma unroll
    for (int e = 0; e < 4; ++e) {
      int j = (e==0) ? j4.x : (e==1) ? j4.y : (e==2) ? j4.z : j4.w;
      float4 p4 = *(const float4*)(P + (size_t)j*ODIM + 4*p);
      float zx = (q4.x + p4.x)*sc4.x + sh4.x;
      float zy = (q4.y + p4.y)*sc4.y + sh4.y;
      float zz = (q4.z + p4.z)*sc4.z + sh4.z;
      float zw = (q4.w + p4.w)*sc4.w + sh4.w;
      float v = (zx/(1.f+expf(-zx)))*wg4.x
              + (zy/(1.f+expf(-zy)))*wg4.y
              + (zz/(1.f+expf(-zz)))*wg4.z
              + (zw/(1.f+expf(-zw)))*wg4.w;
      v += __shfl_xor(v, 1);
      v += __shfl_xor(v, 2);
      v += __shfl_xor(v, 4);
      v += __shfl_xor(v, 8);            // group-wide sum over 64 channels
      float gt = v + bgv;
      if (p == 0) gtbuf[(size_t)i*KNN + 4*grp + e] = gt;
      s += gt; ss += gt*gt;             // per-group partial
    }
  }
  // each group's total enters exactly once (xor16/32 cross groups only)
  s  += __shfl_xor(s, 16);  s  += __shfl_xor(s, 32);
  ss += __shfl_xor(ss, 16); ss += __shfl_xor(ss, 32);
  __shared__ float pw[4], pws[4];
  if (lane == 0) { pw[wid] = s; pws[wid] = ss; }
  __syncthreads();
  if (tid == 0) {
    int set = blockIdx.x & (NSETS-1);
    atomicAdd(&gacc[2*set],   pw[0]+pw[1]+pw[2]+pw[3]);
    atomicAdd(&gacc[2*set+1], pws[0]+pws[1]+pws[2]+pws[3]);
  }
}

// ---------------- final: gsc prologue + softmax over K + weighted sum -------
__global__ __launch_bounds__(256) void final_kernel(
    const float* __restrict__ P, const float* __restrict__ Q,
    const int* __restrict__ idx, const float* __restrict__ scale,
    const float* __restrict__ shift, const float* __restrict__ gtbuf,
    const float* __restrict__ gacc, const float* __restrict__ gg,
    const float* __restrict__ beg, float* __restrict__ out) {
  __shared__ float g2[2];
  if (threadIdx.x == 0) {
    float S = 0.f, SS = 0.f;
    #pragma unroll
    for (int t = 0; t < NSETS; ++t) { S += gacc[2*t]; SS += gacc[2*t+1]; }
    float mu  = S / (float)NEDGE;
    float var = SS / (float)NEDGE - mu*mu;
    float inv = 1.f / sqrtf(var + EPSBN);
    float sg = gg[0] * inv;
    g2[0] = sg; g2[1] = beg[0] - mu * sg;
  }
  __syncthreads();
  int lane = threadIdx.x & 63;
  int wid  = threadIdx.x >> 6;
  int grp  = lane >> 4;
  int p    = lane & 15;
  int i = blockIdx.x * 4 + wid;
  float4 sc4 = *(const float4*)(scale + 4*p);
  float4 sh4 = *(const float4*)(shift + 4*p);
  float gscale = g2[0], gshift = g2[1];
  float4 q4 = *(const float4*)(Q + (size_t)i*ODIM + 4*p);
  int4   j4 = *(const int4*)(idx + (size_t)i*KNN + 4*grp);
  float4 g4 = *(const float4*)(gtbuf + (size_t)i*KNN + 4*grp);

  float z0 = g4.x*gscale + gshift, z1 = g4.y*gscale + gshift;
  float z2 = g4.z*gscale + gshift, z3 = g4.w*gscale + gshift;
  float gt0 = z0/(1.f+expf(-z0)), gt1 = z1/(1.f+expf(-z1));
  float gt2 = z2/(1.f+expf(-z2)), gt3 = z3/(1.f+expf(-z3));
  float m = fmaxf(fmaxf(gt0, gt1), fmaxf(gt2, gt3));
  m = fmaxf(m, __shfl_xor(m, 16));
  m = fmaxf(m, __shfl_xor(m, 32));
  float e0 = expf(gt0-m), e1 = expf(gt1-m), e2 = expf(gt2-m), e3 = expf(gt3-m);
  float se = e0+e1+e2+e3;
  se += __shfl_xor(se, 16);
  se += __shfl_xor(se, 32);
  float invs = 1.f / se;
  float a0 = e0*invs, a1 = e1*invs, a2 = e2*invs, a3 = e3*invs;

  float4 acc = {0.f,0.f,0.f,0.f};
  {
    float4 v = *(const float4*)(P + (size_t)j4.x*ODIM + 4*p);
    float zx=(q4.x+v.x)*sc4.x+sh4.x, zy=(q4.y+v.y)*sc4.y+sh4.y;
    float zz=(q4.z+v.z)*sc4.z+sh4.z, zw=(q4.w+v.w)*sc4.w+sh4.w;
    acc.x += a0*(zx/(1.f+expf(-zx))); acc.y += a0*(zy/(1.f+expf(-zy)));
    acc.z += a0*(zz/(1.f+expf(-zz))); acc.w += a0*(zw/(1.f+expf(-zw)));
  }
  {
    float4 v = *(const float4*)(P + (size_t)j4.y*ODIM + 4*p);
    float zx=(q4.x+v.x)*sc4.x+sh4.x, zy=(q4.y+v.y)*sc4.y+sh4.y;
    float zz=(q4.z+v.z)*sc4.z+sh4.z, zw=(q4.w+v.w)*sc4.w+sh4.w;
    acc.x += a1*(zx/(1.f+expf(-zx))); acc.y += a1*(zy/(1.f+expf(-zy)));
    acc.z += a1*(zz/(1.f+expf(-zz))); acc.w += a1*(zw/(1.f+expf(-zw)));
  }
  {
    float4 v = *(const float4*)(P + (size_t)j4.z*ODIM + 4*p);
    float zx=(q4.x+v.x)*sc4.x+sh4.x, zy=(q4.y+v.y)*sc4.y+sh4.y;
    float zz=(q4.z+v.z)*sc4.z+sh4.z, zw=(q4.w+v.w)*sc4.w+sh4.w;
    acc.x += a2*(zx/(1.f+expf(-zx))); acc.y += a2*(zy/(1.f+expf(-zy)));
    acc.z += a2*(zz/(1.f+expf(-zz))); acc.w += a2*(zw/(1.f+expf(-zw)));
  }
  {
    float4 v = *(const float4*)(P + (size_t)j4.w*ODIM + 4*p);
    float zx=(q4.x+v.x)*sc4.x+sh4.x, zy=(q4.y+v.y)*sc4.y+sh4.y;
    float zz=(q4.z+v.z)*sc4.z+sh4.z, zw=(q4.w+v.w)*sc4.w+sh4.w;
    acc.x += a3*(zx/(1.f+expf(-zx))); acc.y += a3*(zy/(1.f+expf(-zy)));
    acc.z += a3*(zz/(1.f+expf(-zz))); acc.w += a3*(zw/(1.f+expf(-zw)));
  }
  acc.x += __shfl_xor(acc.x,16); acc.x += __shfl_xor(acc.x,32);
  acc.y += __shfl_xor(acc.y,16); acc.y += __shfl_xor(acc.y,32);
  acc.z += __shfl_xor(acc.z,16); acc.z += __shfl_xor(acc.z,32);
  acc.w += __shfl_xor(acc.w,16); acc.w += __shfl_xor(acc.w,32);
  if (grp == 0)
    *(float4*)(out + (size_t)i*ODIM + 4*p) = acc;
}

extern "C" void kernel_launch(void* const* d_in, const int* in_sizes, int n_in,
                              void* d_out, int out_size, void* d_ws, size_t ws_size,
                              hipStream_t stream) {
  const float* x   = (const float*)d_in[0];
  // d_in[1] = batch (unused: sorted equal-size graphs)
  const float* W1  = (const float*)d_in[2];
  const float* b1  = (const float*)d_in[3];
  const float* g1  = (const float*)d_in[4];
  const float* be1 = (const float*)d_in[5];
  const float* Wg  = (const float*)d_in[6];
  const float* bg  = (const float*)d_in[7];
  const float* gg  = (const float*)d_in[8];
  const float* beg = (const float*)d_in[9];
  float* out = (float*)d_out;

  char* ws = (char*)d_ws;
  int*   idx   = (int*)  (ws);                         // 2 MB
  float* P     = (float*)(ws + 2097152);               // 8 MB
  float* Q     = (float*)(ws + 10485760);              // 8 MB
  float* sq    = (float*)(ws + 18874368);              // 128 KB
  float* abuf  = (float*)(ws + 19005440);              // 16x128 f + 32 f
  float* gacc  = abuf + NSETS*128;                     // 32 f
  float* gtbuf = (float*)(ws + 20070400);              // 2 MB   [NEDGE]
  float* scale = (float*)(ws + 22167552);              // 64 f
  float* shift = (float*)(ws + 22167808);              // 64 f

  pq_kernel<<<NTOT/4, 256, 0, stream>>>(x, W1, b1, P, Q, sq, abuf);
  knn_kernel<<<NTOT/KROWS, 256, 0, stream>>>(x, sq, idx);
  stats1a_kernel<<<NBLK_E, 256, 0, stream>>>(P, Q, idx, abuf);
  stats2a_kernel<<<NBLK_E, 256, 0, stream>>>(P, Q, idx, g1, be1, Wg, bg, abuf, scale, shift, gtbuf, gacc);
  final_kernel<<<NTOT/4, 256, 0, stream>>>(P, Q, idx, scale, shift, gtbuf, gacc, gg, beg, out);
}

// Round 14
// 270.141 us; speedup vs baseline: 2.7586x; 1.0250x over previous
//
#include <hip/hip_runtime.h>
#include <math.h>
#include <float.h>

#define BGRAPH 16
#define NPTS   2048
#define CDIM   16
#define ODIM   64
#define KNN    16
#define NTOT   (BGRAPH*NPTS)     // 32768
#define NEDGE  (NTOT*KNN)        // 524288
#define EPSBN  1e-5f
#define NBLK_E 2048              // blocks for edge-stat passes
#define NPW    4                 // nodes per wave in edge-stat passes
#define NSETS  16                // accumulator stripes

// SYNC LESSONS (r10-r12, measured): coop grid.sync ~100us/sync; per-block
// threadfence ~250us total; kernel boundary ~0.4us. Striped atomicAdd
// partials consumed by the next dispatch = free sync.
// LATENCY LESSON (r13): gather passes at VGPR=32 run 2.2x above the VMEM
// issue floor — serial idx->P chains + no load batching. Fix: load all
// node data upfront (addresses ready), launch_bounds(256,4) for reg room.

// ---------------- P = x@W1b, Q = x@(W1a-W1b)+b1, sq = rowsum(x*x) ----------
__global__ __launch_bounds__(256) void pq_kernel(
    const float* __restrict__ x, const float* __restrict__ W1,
    const float* __restrict__ b1,
    float* __restrict__ P, float* __restrict__ Q, float* __restrict__ sq,
    float* __restrict__ abuf) {
  if (blockIdx.x == 0) {
    for (int t = threadIdx.x; t < NSETS*128 + 2*NSETS; t += 256) abuf[t] = 0.f;
  }
  int lane = threadIdx.x & 63;
  int nin  = threadIdx.x >> 6;           // node within block (0..3)
  int node = blockIdx.x * 4 + nin;
  __shared__ float xs[4][CDIM];
  if (threadIdx.x < 4*CDIM) {
    int n = threadIdx.x / CDIM, c = threadIdx.x % CDIM;
    xs[n][c] = x[(blockIdx.x*4 + n)*CDIM + c];
  }
  __syncthreads();
  float p = 0.f, q = b1[lane];
  #pragma unroll
  for (int c = 0; c < CDIM; ++c) {
    float xv = xs[nin][c];
    float wb = W1[(c+CDIM)*ODIM + lane];
    float wa = W1[c*ODIM + lane];
    p += xv * wb;
    q += xv * (wa - wb);
  }
  P[node*ODIM + lane] = p;
  Q[node*ODIM + lane] = q;
  if (lane == 0) {
    float s = 0.f;
    #pragma unroll
    for (int c = 0; c < CDIM; ++c) { float xv = xs[nin][c]; s += xv*xv; }
    sq[node] = s;
  }
}

// ---------------- kNN: hybrid 2 rows/wave (r13-verified, FROZEN) ------------
// 109.7us, VGPR=68, WRITE=2MB. Row A d[32] in regs (r1 shape), row B in LDS
// dB[s][tid]. Near structural floor: selection shuffles are LDS-pipe ops.
#define KROWS 8
__device__ __forceinline__ unsigned long long packkey(float dv, int j) {
  unsigned ub = __float_as_uint(dv);
  ub ^= ((unsigned)((int)ub >> 31)) | 0x80000000u;   // monotone f32->u32
  return (((unsigned long long)ub) << 32) | (unsigned)j;
}
__device__ __forceinline__ float rfl(float v) {
  return __uint_as_float(__builtin_amdgcn_readfirstlane(__float_as_uint(v)));
}

__global__ __launch_bounds__(256, 3) void knn_kernel(
    const float* __restrict__ x, const float* __restrict__ sq,
    int* __restrict__ idxOut) {
  __shared__ float sT16[CDIM][256];                 // transposed tile, 16 KB
  __shared__ float dB[32][256];                     // row-B dists, 32 KB
  __shared__ unsigned long long skey[4][64];        // per-wave survivor keys
  __shared__ int scnt[4];
  const int tid  = threadIdx.x;
  const int lane = tid & 63;
  const int w    = tid >> 6;
  const int blocksPerGraph = NPTS / KROWS;          // 256
  const int g     = blockIdx.x / blocksPerGraph;
  const int rb    = (blockIdx.x % blocksPerGraph) * KROWS;
  const int gbase = g * NPTS;
  const int r0    = rb + w*2;                       // rows r0 (A), r0+1 (B)

  // wave-uniform row features -> SGPRs
  float ta[CDIM], tb[CDIM]; float tsqA, tsqB;
  {
    const float4* tp = (const float4*)(x + (size_t)(gbase + r0)*CDIM);
    float4 t0 = tp[0], t1 = tp[1], t2 = tp[2], t3 = tp[3];
    ta[0]=rfl(t0.x);  ta[1]=rfl(t0.y);  ta[2]=rfl(t0.z);  ta[3]=rfl(t0.w);
    ta[4]=rfl(t1.x);  ta[5]=rfl(t1.y);  ta[6]=rfl(t1.z);  ta[7]=rfl(t1.w);
    ta[8]=rfl(t2.x);  ta[9]=rfl(t2.y);  ta[10]=rfl(t2.z); ta[11]=rfl(t2.w);
    ta[12]=rfl(t3.x); ta[13]=rfl(t3.y); ta[14]=rfl(t3.z); ta[15]=rfl(t3.w);
    tsqA = rfl(sq[gbase + r0]);
    const float4* up = (const float4*)(x + (size_t)(gbase + r0 + 1)*CDIM);
    float4 u0 = up[0], u1 = up[1], u2 = up[2], u3 = up[3];
    tb[0]=rfl(u0.x);  tb[1]=rfl(u0.y);  tb[2]=rfl(u0.z);  tb[3]=rfl(u0.w);
    tb[4]=rfl(u1.x);  tb[5]=rfl(u1.y);  tb[6]=rfl(u1.z);  tb[7]=rfl(u1.w);
    tb[8]=rfl(u2.x);  tb[9]=rfl(u2.y);  tb[10]=rfl(u2.z); tb[11]=rfl(u2.w);
    tb[12]=rfl(u3.x); tb[13]=rfl(u3.y); tb[14]=rfl(u3.z); tb[15]=rfl(u3.w);
    tsqB = rfl(sq[gbase + r0 + 1]);
  }

  float d[32];                                      // row A only (r1 shape)

  // prefetch tile 0 into regs (r1-proven staging structure)
  float4 a0, a1, a2, a3;
  {
    const float4* xp = (const float4*)(x + (size_t)(gbase + tid)*CDIM);
    a0 = xp[0]; a1 = xp[1]; a2 = xp[2]; a3 = xp[3];
  }

  #pragma unroll
  for (int t = 0; t < NPTS/256; ++t) {
    __syncthreads();                                // prev tile reads done
    sT16[0][tid]=a0.x;  sT16[1][tid]=a0.y;  sT16[2][tid]=a0.z;  sT16[3][tid]=a0.w;
    sT16[4][tid]=a1.x;  sT16[5][tid]=a1.y;  sT16[6][tid]=a1.z;  sT16[7][tid]=a1.w;
    sT16[8][tid]=a2.x;  sT16[9][tid]=a2.y;  sT16[10][tid]=a2.z; sT16[11][tid]=a2.w;
    sT16[12][tid]=a3.x; sT16[13][tid]=a3.y; sT16[14][tid]=a3.z; sT16[15][tid]=a3.w;
    __syncthreads();
    if (t < NPTS/256 - 1) {                         // issue next-tile loads early
      const float4* xp = (const float4*)(x + (size_t)(gbase + (t+1)*256 + tid)*CDIM);
      a0 = xp[0]; a1 = xp[1]; a2 = xp[2]; a3 = xp[3];
    }

    float4 sq4 = *(const float4*)(sq + gbase + t*256 + 4*lane);
    float sqv[4] = {sq4.x, sq4.y, sq4.z, sq4.w};

    float dotA[4] = {0.f,0.f,0.f,0.f};
    float dotB[4] = {0.f,0.f,0.f,0.f};
    #pragma unroll
    for (int c = 0; c < CDIM; ++c) {
      float4 cv = *(const float4*)(&sT16[c][4*lane]);   // shared by both rows
      float xa = ta[c], xb = tb[c];                 // SGPR operands
      dotA[0] += xa*cv.x; dotA[1] += xa*cv.y; dotA[2] += xa*cv.z; dotA[3] += xa*cv.w;
      dotB[0] += xb*cv.x; dotB[1] += xb*cv.y; dotB[2] += xb*cv.z; dotB[3] += xb*cv.w;
    }
    #pragma unroll
    for (int rr = 0; rr < 4; ++rr) {
      d[t*4 + rr] = tsqA + sqv[rr] - 2.f*dotA[rr];          // regs (row A)
      dB[t*4 + rr][tid] = tsqB + sqv[rr] - 2.f*dotB[rr];    // LDS  (row B)
    }
  }

  // -------- SELECT row A (registers — r1-proven body) --------
  {
    float lmin = d[0];
    #pragma unroll
    for (int s = 1; s < 32; ++s) lmin = fminf(lmin, d[s]);

    float v = lmin;
    #pragma unroll
    for (int k = 2; k <= 64; k <<= 1) {
      #pragma unroll
      for (int j = k >> 1; j > 0; j >>= 1) {
        float o = __shfl_xor(v, j);
        bool asc   = ((lane & k) == 0);
        bool lower = ((lane & j) == 0);
        float mn = fminf(v, o), mx = fmaxf(v, o);
        v = (asc == lower) ? mn : mx;
      }
    }
    float T = __shfl(v, 15);

    if (lane == 0) scnt[w] = 0;
    #pragma unroll
    for (int s = 0; s < 32; ++s) {
      if (d[s] <= T) {
        int p = atomicAdd(&scnt[w], 1);
        if (p < 64) {
          int j = (s >> 2)*256 + 4*lane + (s & 3);
          skey[w][p] = packkey(d[s], j);
        }
      }
    }
    int M = scnt[w];
    int row = gbase + r0;

    if (M <= 64) {
      unsigned long long key = (lane < M) ? skey[w][lane] : ~0ull;
      #pragma unroll
      for (int k = 2; k <= 64; k <<= 1) {
        #pragma unroll
        for (int j = k >> 1; j > 0; j >>= 1) {
          unsigned long long o = __shfl_xor(key, j);
          bool asc   = ((lane & k) == 0);
          bool lower = ((lane & j) == 0);
          unsigned long long mn = (key < o) ? key : o;
          unsigned long long mx = (key < o) ? o : key;
          key = (asc == lower) ? mn : mx;
        }
      }
      if (lane < KNN)
        idxOut[(size_t)row*KNN + lane] = gbase + (int)(key & 0xffffffffu);
    } else {
      for (int sel = 0; sel < KNN; ++sel) {
        unsigned long long lb = ~0ull;
        #pragma unroll
        for (int s = 0; s < 32; ++s) {
          int j = (s >> 2)*256 + 4*lane + (s & 3);
          unsigned long long ks = packkey(d[s], j);
          if (ks < lb) lb = ks;
        }
        #pragma unroll
        for (int off = 32; off > 0; off >>= 1) {
          unsigned long long o = __shfl_xor(lb, off);
          if (o < lb) lb = o;
        }
        if (lane == 0)
          idxOut[(size_t)row*KNN + sel] = gbase + (int)(lb & 0xffffffffu);
        #pragma unroll
        for (int s = 0; s < 32; ++s) {
          int j = (s >> 2)*256 + 4*lane + (s & 3);
          if (packkey(d[s], j) == lb) d[s] = FLT_MAX;
        }
      }
    }
  }

  // -------- SELECT row B (distances in dB[s][tid], same algorithm) --------
  {
    float lmin = dB[0][tid];
    #pragma unroll
    for (int s = 1; s < 32; ++s) lmin = fminf(lmin, dB[s][tid]);

    float v = lmin;
    #pragma unroll
    for (int k = 2; k <= 64; k <<= 1) {
      #pragma unroll
      for (int j = k >> 1; j > 0; j >>= 1) {
        float o = __shfl_xor(v, j);
        bool asc   = ((lane & k) == 0);
        bool lower = ((lane & j) == 0);
        float mn = fminf(v, o), mx = fmaxf(v, o);
        v = (asc == lower) ? mn : mx;
      }
    }
    float T = __shfl(v, 15);

    if (lane == 0) scnt[w] = 0;
    #pragma unroll
    for (int s = 0; s < 32; ++s) {
      float dv = dB[s][tid];
      if (dv <= T) {
        int p = atomicAdd(&scnt[w], 1);
        if (p < 64) {
          int j = (s >> 2)*256 + 4*lane + (s & 3);
          skey[w][p] = packkey(dv, j);
        }
      }
    }
    int M = scnt[w];
    int row = gbase + r0 + 1;

    if (M <= 64) {
      unsigned long long key = (lane < M) ? skey[w][lane] : ~0ull;
      #pragma unroll
      for (int k = 2; k <= 64; k <<= 1) {
        #pragma unroll
        for (int j = k >> 1; j > 0; j >>= 1) {
          unsigned long long o = __shfl_xor(key, j);
          bool asc   = ((lane & k) == 0);
          bool lower = ((lane & j) == 0);
          unsigned long long mn = (key < o) ? key : o;
          unsigned long long mx = (key < o) ? o : key;
          key = (asc == lower) ? mn : mx;
        }
      }
      if (lane < KNN)
        idxOut[(size_t)row*KNN + lane] = gbase + (int)(key & 0xffffffffu);
    } else {
      for (int sel = 0; sel < KNN; ++sel) {
        unsigned long long lb = ~0ull;
        #pragma unroll
        for (int s = 0; s < 32; ++s) {
          int j = (s >> 2)*256 + 4*lane + (s & 3);
          unsigned long long ks = packkey(dB[s][tid], j);
          if (ks < lb) lb = ks;
        }
        #pragma unroll
        for (int off = 32; off > 0; off >>= 1) {
          unsigned long long o = __shfl_xor(lb, off);
          if (o < lb) lb = o;
        }
        if (lane == 0)
          idxOut[(size_t)row*KNN + sel] = gbase + (int)(lb & 0xffffffffu);
        #pragma unroll
        for (int s = 0; s < 32; ++s) {
          int j = (s >> 2)*256 + 4*lane + (s & 3);
          if (packkey(dB[s][tid], j) == lb) dB[s][tid] = FLT_MAX;
        }
      }
    }
  }
}

// ---------------- stats pass 1: batched loads + striped-atomic tail ---------
// All q4/j4 loaded upfront (kills cross-iteration idx->P chain); every
// P-gather address ready before first accumulate -> scheduler hoists loads.
// launch_bounds(256,4): VGPR cap 128, demand ~90 -> no spill (WRITE canary).
__global__ __launch_bounds__(256, 4) void stats1a_kernel(
    const float* __restrict__ P, const float* __restrict__ Q,
    const int* __restrict__ idx, float* __restrict__ abuf) {
  int tid  = threadIdx.x;
  int lane = tid & 63;
  int wid  = tid >> 6;
  int grp  = lane >> 4;                 // edge-quad slot 0..3
  int p    = lane & 15;                 // channel quad 0..15
  int gw   = blockIdx.x * 4 + wid;
  int n0 = gw * NPW;
  float4 q4v[NPW]; int4 j4v[NPW];
  #pragma unroll
  for (int ii = 0; ii < NPW; ++ii) {
    int i = n0 + ii;
    q4v[ii] = *(const float4*)(Q + (size_t)i*ODIM + 4*p);
    j4v[ii] = *(const int4*)(idx + (size_t)i*KNN + 4*grp);
  }
  float4 s4  = {0.f,0.f,0.f,0.f};
  float4 ss4 = {0.f,0.f,0.f,0.f};
  #pragma unroll
  for (int ii = 0; ii < NPW; ++ii) {
    float4 q4 = q4v[ii];
    float4 v0 = *(const float4*)(P + (size_t)j4v[ii].x*ODIM + 4*p);
    float4 v1 = *(const float4*)(P + (size_t)j4v[ii].y*ODIM + 4*p);
    float4 v2 = *(const float4*)(P + (size_t)j4v[ii].z*ODIM + 4*p);
    float4 v3 = *(const float4*)(P + (size_t)j4v[ii].w*ODIM + 4*p);
    {
      float hx=q4.x+v0.x, hy=q4.y+v0.y, hz=q4.z+v0.z, hw=q4.w+v0.w;
      s4.x+=hx; s4.y+=hy; s4.z+=hz; s4.w+=hw;
      ss4.x+=hx*hx; ss4.y+=hy*hy; ss4.z+=hz*hz; ss4.w+=hw*hw;
    }
    {
      float hx=q4.x+v1.x, hy=q4.y+v1.y, hz=q4.z+v1.z, hw=q4.w+v1.w;
      s4.x+=hx; s4.y+=hy; s4.z+=hz; s4.w+=hw;
      ss4.x+=hx*hx; ss4.y+=hy*hy; ss4.z+=hz*hz; ss4.w+=hw*hw;
    }
    {
      float hx=q4.x+v2.x, hy=q4.y+v2.y, hz=q4.z+v2.z, hw=q4.w+v2.w;
      s4.x+=hx; s4.y+=hy; s4.z+=hz; s4.w+=hw;
      ss4.x+=hx*hx; ss4.y+=hy*hy; ss4.z+=hz*hz; ss4.w+=hw*hw;
    }
    {
      float hx=q4.x+v3.x, hy=q4.y+v3.y, hz=q4.z+v3.z, hw=q4.w+v3.w;
      s4.x+=hx; s4.y+=hy; s4.z+=hz; s4.w+=hw;
      ss4.x+=hx*hx; ss4.y+=hy*hy; ss4.z+=hz*hz; ss4.w+=hw*hw;
    }
  }
  // cross-group reduce (each group's partial enters ONCE — r7 post-mortem)
  s4.x  += __shfl_xor(s4.x,16);  s4.x  += __shfl_xor(s4.x,32);
  s4.y  += __shfl_xor(s4.y,16);  s4.y  += __shfl_xor(s4.y,32);
  s4.z  += __shfl_xor(s4.z,16);  s4.z  += __shfl_xor(s4.z,32);
  s4.w  += __shfl_xor(s4.w,16);  s4.w  += __shfl_xor(s4.w,32);
  ss4.x += __shfl_xor(ss4.x,16); ss4.x += __shfl_xor(ss4.x,32);
  ss4.y += __shfl_xor(ss4.y,16); ss4.y += __shfl_xor(ss4.y,32);
  ss4.z += __shfl_xor(ss4.z,16); ss4.z += __shfl_xor(ss4.z,32);
  ss4.w += __shfl_xor(ss4.w,16); ss4.w += __shfl_xor(ss4.w,32);
  __shared__ float ls[4][ODIM], lss[4][ODIM];
  if (grp == 0) {
    *(float4*)&ls[wid][4*p]  = s4;
    *(float4*)&lss[wid][4*p] = ss4;
  }
  __syncthreads();
  if (tid < 2*ODIM) {
    float a;
    if (tid < ODIM) a = ls[0][tid] + ls[1][tid] + ls[2][tid] + ls[3][tid];
    else { int o = tid - ODIM; a = lss[0][o] + lss[1][o] + lss[2][o] + lss[3][o]; }
    atomicAdd(&abuf[(blockIdx.x & (NSETS-1))*128 + tid], a);
  }
}

// ---------------- stats pass 2: BN prologue + batched gate pass -------------
// Node loads issued BEFORE the prologue barrier (fly under the abuf reduce).
__global__ __launch_bounds__(256, 4) void stats2a_kernel(
    const float* __restrict__ P, const float* __restrict__ Q,
    const int* __restrict__ idx,
    const float* __restrict__ g1, const float* __restrict__ be1,
    const float* __restrict__ Wg, const float* __restrict__ bg,
    const float* __restrict__ abuf, float* __restrict__ scale,
    float* __restrict__ shift, float* __restrict__ gtbuf,
    float* __restrict__ gacc) {
  int tid  = threadIdx.x;
  int lane = tid & 63;
  int wid  = tid >> 6;
  int grp  = lane >> 4;                 // edge-quad slot
  int p    = lane & 15;                 // channel quad
  int gw   = blockIdx.x * 4 + wid;
  int n0 = gw * NPW;
  // issue node loads first — they complete during the BN prologue
  float4 q4v[NPW]; int4 j4v[NPW];
  #pragma unroll
  for (int ii = 0; ii < NPW; ++ii) {
    int i = n0 + ii;
    q4v[ii] = *(const float4*)(Q + (size_t)i*ODIM + 4*p);
    j4v[ii] = *(const int4*)(idx + (size_t)i*KNN + 4*grp);
  }
  __shared__ __align__(16) float s_sc[ODIM], s_sh[ODIM];
  __shared__ float red[2*ODIM];
  if (tid < 2*ODIM) {
    float a = 0.f;
    #pragma unroll
    for (int t = 0; t < NSETS; ++t) a += abuf[t*128 + tid];   // deterministic order
    red[tid] = a;
  }
  __syncthreads();
  if (tid < ODIM) {
    float mu  = red[tid] / (float)NEDGE;
    float var = red[ODIM+tid] / (float)NEDGE - mu*mu;
    float inv = 1.0f / sqrtf(var + EPSBN);
    float sc = g1[tid] * inv;
    float sh = be1[tid] - mu * sc;
    s_sc[tid] = sc; s_sh[tid] = sh;
    if (blockIdx.x == 0) { scale[tid] = sc; shift[tid] = sh; }  // for final
  }
  __syncthreads();

  float4 sc4 = *(const float4*)&s_sc[4*p];
  float4 sh4 = *(const float4*)&s_sh[4*p];
  float4 wg4 = *(const float4*)(Wg + 4*p);
  float bgv = bg[0];
  float s = 0.f, ss = 0.f;
  #pragma unroll
  for (int ii = 0; ii < NPW; ++ii) {
    int i = n0 + ii;
    float4 q4 = q4v[ii];
    float4 pv[4];
    pv[0] = *(const float4*)(P + (size_t)j4v[ii].x*ODIM + 4*p);
    pv[1] = *(const float4*)(P + (size_t)j4v[ii].y*ODIM + 4*p);
    pv[2] = *(const float4*)(P + (size_t)j4v[ii].z*ODIM + 4*p);
    pv[3] = *(const float4*)(P + (size_t)j4v[ii].w*ODIM + 4*p);
    #pragma unroll
    for (int e = 0; e < 4; ++e) {
      float4 p4 = pv[e];
      float zx = (q4.x + p4.x)*sc4.x + sh4.x;
      float zy = (q4.y + p4.y)*sc4.y + sh4.y;
      float zz = (q4.z + p4.z)*sc4.z + sh4.z;
      float zw = (q4.w + p4.w)*sc4.w + sh4.w;
      float v = (zx/(1.f+expf(-zx)))*wg4.x
              + (zy/(1.f+expf(-zy)))*wg4.y
              + (zz/(1.f+expf(-zz)))*wg4.z
              + (zw/(1.f+expf(-zw)))*wg4.w;
      v += __shfl_xor(v, 1);
      v += __shfl_xor(v, 2);
      v += __shfl_xor(v, 4);
      v += __shfl_xor(v, 8);            // group-wide sum over 64 channels
      float gt = v + bgv;
      if (p == 0) gtbuf[(size_t)i*KNN + 4*grp + e] = gt;
      s += gt; ss += gt*gt;             // per-group partial
    }
  }
  // each group's total enters exactly once (xor16/32 cross groups only)
  s  += __shfl_xor(s, 16);  s  += __shfl_xor(s, 32);
  ss += __shfl_xor(ss, 16); ss += __shfl_xor(ss, 32);
  __shared__ float pw[4], pws[4];
  if (lane == 0) { pw[wid] = s; pws[wid] = ss; }
  __syncthreads();
  if (tid == 0) {
    int set = blockIdx.x & (NSETS-1);
    atomicAdd(&gacc[2*set],   pw[0]+pw[1]+pw[2]+pw[3]);
    atomicAdd(&gacc[2*set+1], pws[0]+pws[1]+pws[2]+pws[3]);
  }
}

// ---------------- final: 2 nodes/wave, batched loads ------------------------
// 4096 blocks; wave processes nodes iA=blk*8+wid*2, iB=iA+1. All q/j/g and
// both nodes' 8 P-gathers issue upfront; compute A then B.
__global__ __launch_bounds__(256, 4) void final_kernel(
    const float* __restrict__ P, const float* __restrict__ Q,
    const int* __restrict__ idx, const float* __restrict__ scale,
    const float* __restrict__ shift, const float* __restrict__ gtbuf,
    const float* __restrict__ gacc, const float* __restrict__ gg,
    const float* __restrict__ beg, float* __restrict__ out) {
  __shared__ float g2[2];
  if (threadIdx.x == 0) {
    float S = 0.f, SS = 0.f;
    #pragma unroll
    for (int t = 0; t < NSETS; ++t) { S += gacc[2*t]; SS += gacc[2*t+1]; }
    float mu  = S / (float)NEDGE;
    float var = SS / (float)NEDGE - mu*mu;
    float inv = 1.f / sqrtf(var + EPSBN);
    float sg = gg[0] * inv;
    g2[0] = sg; g2[1] = beg[0] - mu * sg;
  }
  __syncthreads();
  int lane = threadIdx.x & 63;
  int wid  = threadIdx.x >> 6;
  int grp  = lane >> 4;
  int p    = lane & 15;
  int iA = blockIdx.x * 8 + wid * 2;
  int iB = iA + 1;
  float4 sc4 = *(const float4*)(scale + 4*p);
  float4 sh4 = *(const float4*)(shift + 4*p);
  float gscale = g2[0], gshift = g2[1];
  // batched loads for BOTH nodes
  float4 qA = *(const float4*)(Q + (size_t)iA*ODIM + 4*p);
  float4 qB = *(const float4*)(Q + (size_t)iB*ODIM + 4*p);
  int4   jA = *(const int4*)(idx + (size_t)iA*KNN + 4*grp);
  int4   jB = *(const int4*)(idx + (size_t)iB*KNN + 4*grp);
  float4 gA = *(const float4*)(gtbuf + (size_t)iA*KNN + 4*grp);
  float4 gB = *(const float4*)(gtbuf + (size_t)iB*KNN + 4*grp);
  float4 pA0 = *(const float4*)(P + (size_t)jA.x*ODIM + 4*p);
  float4 pA1 = *(const float4*)(P + (size_t)jA.y*ODIM + 4*p);
  float4 pA2 = *(const float4*)(P + (size_t)jA.z*ODIM + 4*p);
  float4 pA3 = *(const float4*)(P + (size_t)jA.w*ODIM + 4*p);
  float4 pB0 = *(const float4*)(P + (size_t)jB.x*ODIM + 4*p);
  float4 pB1 = *(const float4*)(P + (size_t)jB.y*ODIM + 4*p);
  float4 pB2 = *(const float4*)(P + (size_t)jB.z*ODIM + 4*p);
  float4 pB3 = *(const float4*)(P + (size_t)jB.w*ODIM + 4*p);

  // ---- node A ----
  {
    float z0 = gA.x*gscale + gshift, z1 = gA.y*gscale + gshift;
    float z2 = gA.z*gscale + gshift, z3 = gA.w*gscale + gshift;
    float gt0 = z0/(1.f+expf(-z0)), gt1 = z1/(1.f+expf(-z1));
    float gt2 = z2/(1.f+expf(-z2)), gt3 = z3/(1.f+expf(-z3));
    float m = fmaxf(fmaxf(gt0, gt1), fmaxf(gt2, gt3));
    m = fmaxf(m, __shfl_xor(m, 16));
    m = fmaxf(m, __shfl_xor(m, 32));
    float e0 = expf(gt0-m), e1 = expf(gt1-m), e2 = expf(gt2-m), e3 = expf(gt3-m);
    float se = e0+e1+e2+e3;
    se += __shfl_xor(se, 16);
    se += __shfl_xor(se, 32);
    float invs = 1.f / se;
    float a0 = e0*invs, a1 = e1*invs, a2 = e2*invs, a3 = e3*invs;
    float4 acc = {0.f,0.f,0.f,0.f};
    {
      float zx=(qA.x+pA0.x)*sc4.x+sh4.x, zy=(qA.y+pA0.y)*sc4.y+sh4.y;
      float zz=(qA.z+pA0.z)*sc4.z+sh4.z, zw=(qA.w+pA0.w)*sc4.w+sh4.w;
      acc.x += a0*(zx/(1.f+expf(-zx))); acc.y += a0*(zy/(1.f+expf(-zy)));
      acc.z += a0*(zz/(1.f+expf(-zz))); acc.w += a0*(zw/(1.f+expf(-zw)));
    }
    {
      float zx=(qA.x+pA1.x)*sc4.x+sh4.x, zy=(qA.y+pA1.y)*sc4.y+sh4.y;
      float zz=(qA.z+pA1.z)*sc4.z+sh4.z, zw=(qA.w+pA1.w)*sc4.w+sh4.w;
      acc.x += a1*(zx/(1.f+expf(-zx))); acc.y += a1*(zy/(1.f+expf(-zy)));
      acc.z += a1*(zz/(1.f+expf(-zz))); acc.w += a1*(zw/(1.f+expf(-zw)));
    }
    {
      float zx=(qA.x+pA2.x)*sc4.x+sh4.x, zy=(qA.y+pA2.y)*sc4.y+sh4.y;
      float zz=(qA.z+pA2.z)*sc4.z+sh4.z, zw=(qA.w+pA2.w)*sc4.w+sh4.w;
      acc.x += a2*(zx/(1.f+expf(-zx))); acc.y += a2*(zy/(1.f+expf(-zy)));
      acc.z += a2*(zz/(1.f+expf(-zz))); acc.w += a2*(zw/(1.f+expf(-zw)));
    }
    {
      float zx=(qA.x+pA3.x)*sc4.x+sh4.x, zy=(qA.y+pA3.y)*sc4.y+sh4.y;
      float zz=(qA.z+pA3.z)*sc4.z+sh4.z, zw=(qA.w+pA3.w)*sc4.w+sh4.w;
      acc.x += a3*(zx/(1.f+expf(-zx))); acc.y += a3*(zy/(1.f+expf(-zy)));
      acc.z += a3*(zz/(1.f+expf(-zz))); acc.w += a3*(zw/(1.f+expf(-zw)));
    }
    acc.x += __shfl_xor(acc.x,16); acc.x += __shfl_xor(acc.x,32);
    acc.y += __shfl_xor(acc.y,16); acc.y += __shfl_xor(acc.y,32);
    acc.z += __shfl_xor(acc.z,16); acc.z += __shfl_xor(acc.z,32);
    acc.w += __shfl_xor(acc.w,16); acc.w += __shfl_xor(acc.w,32);
    if (grp == 0)
      *(float4*)(out + (size_t)iA*ODIM + 4*p) = acc;
  }

  // ---- node B ----
  {
    float z0 = gB.x*gscale + gshift, z1 = gB.y*gscale + gshift;
    float z2 = gB.z*gscale + gshift, z3 = gB.w*gscale + gshift;
    float gt0 = z0/(1.f+expf(-z0)), gt1 = z1/(1.f+expf(-z1));
    float gt2 = z2/(1.f+expf(-z2)), gt3 = z3/(1.f+expf(-z3));
    float m = fmaxf(fmaxf(gt0, gt1), fmaxf(gt2, gt3));
    m = fmaxf(m, __shfl_xor(m, 16));
    m = fmaxf(m, __shfl_xor(m, 32));
    float e0 = expf(gt0-m), e1 = expf(gt1-m), e2 = expf(gt2-m), e3 = expf(gt3-m);
    float se = e0+e1+e2+e3;
    se += __shfl_xor(se, 16);
    se += __shfl_xor(se, 32);
    float invs = 1.f / se;
    float a0 = e0*invs, a1 = e1*invs, a2 = e2*invs, a3 = e3*invs;
    float4 acc = {0.f,0.f,0.f,0.f};
    {
      float zx=(qB.x+pB0.x)*sc4.x+sh4.x, zy=(qB.y+pB0.y)*sc4.y+sh4.y;
      float zz=(qB.z+pB0.z)*sc4.z+sh4.z, zw=(qB.w+pB0.w)*sc4.w+sh4.w;
      acc.x += a0*(zx/(1.f+expf(-zx))); acc.y += a0*(zy/(1.f+expf(-zy)));
      acc.z += a0*(zz/(1.f+expf(-zz))); acc.w += a0*(zw/(1.f+expf(-zw)));
    }
    {
      float zx=(qB.x+pB1.x)*sc4.x+sh4.x, zy=(qB.y+pB1.y)*sc4.y+sh4.y;
      float zz=(qB.z+pB1.z)*sc4.z+sh4.z, zw=(qB.w+pB1.w)*sc4.w+sh4.w;
      acc.x += a1*(zx/(1.f+expf(-zx))); acc.y += a1*(zy/(1.f+expf(-zy)));
      acc.z += a1*(zz/(1.f+expf(-zz))); acc.w += a1*(zw/(1.f+expf(-zw)));
    }
    {
      float zx=(qB.x+pB2.x)*sc4.x+sh4.x, zy=(qB.y+pB2.y)*sc4.y+sh4.y;
      float zz=(qB.z+pB2.z)*sc4.z+sh4.z, zw=(qB.w+pB2.w)*sc4.w+sh4.w;
      acc.x += a2*(zx/(1.f+expf(-zx))); acc.y += a2*(zy/(1.f+expf(-zy)));
      acc.z += a2*(zz/(1.f+expf(-zz))); acc.w += a2*(zw/(1.f+expf(-zw)));
    }
    {
      float zx=(qB.x+pB3.x)*sc4.x+sh4.x, zy=(qB.y+pB3.y)*sc4.y+sh4.y;
      float zz=(qB.z+pB3.z)*sc4.z+sh4.z, zw=(qB.w+pB3.w)*sc4.w+sh4.w;
      acc.x += a3*(zx/(1.f+expf(-zx))); acc.y += a3*(zy/(1.f+expf(-zy)));
      acc.z += a3*(zz/(1.f+expf(-zz))); acc.w += a3*(zw/(1.f+expf(-zw)));
    }
    acc.x += __shfl_xor(acc.x,16); acc.x += __shfl_xor(acc.x,32);
    acc.y += __shfl_xor(acc.y,16); acc.y += __shfl_xor(acc.y,32);
    acc.z += __shfl_xor(acc.z,16); acc.z += __shfl_xor(acc.z,32);
    acc.w += __shfl_xor(acc.w,16); acc.w += __shfl_xor(acc.w,32);
    if (grp == 0)
      *(float4*)(out + (size_t)iB*ODIM + 4*p) = acc;
  }
}

extern "C" void kernel_launch(void* const* d_in, const int* in_sizes, int n_in,
                              void* d_out, int out_size, void* d_ws, size_t ws_size,
                              hipStream_t stream) {
  const float* x   = (const float*)d_in[0];
  // d_in[1] = batch (unused: sorted equal-size graphs)
  const float* W1  = (const float*)d_in[2];
  const float* b1  = (const float*)d_in[3];
  const float* g1  = (const float*)d_in[4];
  const float* be1 = (const float*)d_in[5];
  const float* Wg  = (const float*)d_in[6];
  const float* bg  = (const float*)d_in[7];
  const float* gg  = (const float*)d_in[8];
  const float* beg = (const float*)d_in[9];
  float* out = (float*)d_out;

  char* ws = (char*)d_ws;
  int*   idx   = (int*)  (ws);                         // 2 MB
  float* P     = (float*)(ws + 2097152);               // 8 MB
  float* Q     = (float*)(ws + 10485760);              // 8 MB
  float* sq    = (float*)(ws + 18874368);              // 128 KB
  float* abuf  = (float*)(ws + 19005440);              // 16x128 f + 32 f
  float* gacc  = abuf + NSETS*128;                     // 32 f
  float* gtbuf = (float*)(ws + 20070400);              // 2 MB   [NEDGE]
  float* scale = (float*)(ws + 22167552);              // 64 f
  float* shift = (float*)(ws + 22167808);              // 64 f

  pq_kernel<<<NTOT/4, 256, 0, stream>>>(x, W1, b1, P, Q, sq, abuf);
  knn_kernel<<<NTOT/KROWS, 256, 0, stream>>>(x, sq, idx);
  stats1a_kernel<<<NBLK_E, 256, 0, stream>>>(P, Q, idx, abuf);
  stats2a_kernel<<<NBLK_E, 256, 0, stream>>>(P, Q, idx, g1, be1, Wg, bg, abuf, scale, shift, gtbuf, gacc);
  final_kernel<<<NTOT/8, 256, 0, stream>>>(P, Q, idx, scale, shift, gtbuf, gacc, gg, beg, out);
}

// Round 15
// 268.800 us; speedup vs baseline: 2.7724x; 1.0050x over previous
//
#include <hip/hip_runtime.h>
#include <math.h>
#include <float.h>

#define BGRAPH 16
#define NPTS   2048
#define CDIM   16
#define ODIM   64
#define KNN    16
#define NTOT   (BGRAPH*NPTS)     // 32768
#define NEDGE  (NTOT*KNN)        // 524288
#define EPSBN  1e-5f
#define NBLK_E 2048              // blocks for edge-stat passes
#define NPW    4                 // nodes per wave in edge-stat passes
#define NSETS  16                // accumulator stripes

// SYNC LESSONS (r10-r12, measured): coop grid.sync ~100us/sync; per-block
// threadfence ~250us total; kernel boundary ~0.4us. Striped atomicAdd
// partials consumed by the next dispatch = free sync.
// r14 LESSON: tail gather passes are VMEM-LATENCY bound (P=8MB > 4MB/XCD L2
// -> IC latency), not issue-bound; batching gained only 7us. r15 move:
// fuse stats1 into knn's idle VMEM pipe (knn FETCH=81GB/s, 1.3% HBM).

// ---------------- P = x@W1b, Q = x@(W1a-W1b)+b1, sq = rowsum(x*x) ----------
__global__ __launch_bounds__(256) void pq_kernel(
    const float* __restrict__ x, const float* __restrict__ W1,
    const float* __restrict__ b1,
    float* __restrict__ P, float* __restrict__ Q, float* __restrict__ sq,
    float* __restrict__ abuf) {
  if (blockIdx.x == 0) {
    for (int t = threadIdx.x; t < NSETS*128 + 2*NSETS; t += 256) abuf[t] = 0.f;
  }
  int lane = threadIdx.x & 63;
  int nin  = threadIdx.x >> 6;           // node within block (0..3)
  int node = blockIdx.x * 4 + nin;
  __shared__ float xs[4][CDIM];
  if (threadIdx.x < 4*CDIM) {
    int n = threadIdx.x / CDIM, c = threadIdx.x % CDIM;
    xs[n][c] = x[(blockIdx.x*4 + n)*CDIM + c];
  }
  __syncthreads();
  float p = 0.f, q = b1[lane];
  #pragma unroll
  for (int c = 0; c < CDIM; ++c) {
    float xv = xs[nin][c];
    float wb = W1[(c+CDIM)*ODIM + lane];
    float wa = W1[c*ODIM + lane];
    p += xv * wb;
    q += xv * (wa - wb);
  }
  P[node*ODIM + lane] = p;
  Q[node*ODIM + lane] = q;
  if (lane == 0) {
    float s = 0.f;
    #pragma unroll
    for (int c = 0; c < CDIM; ++c) { float xv = xs[nin][c]; s += xv*xv; }
    sq[node] = s;
  }
}

// ---------------- kNN (r13 body, FROZEN) + fused stats1 epilogue ------------
// Main loop + selection byte-identical to r13/r14 (109.7us verified). After
// both SELECTs: each wave gathers its 2 rows' neighbors' P rows (grouped
// stats1a layout), block-combines in LDS (reusing dead dB — no LDS growth),
// striped-atomicAdds into abuf. Overlaps knn's idle VMEM pipe; removes the
// stats1a dispatch. REVERT RULE: knn>155us or WRITE>10MB -> r14.
#define KROWS 8
__device__ __forceinline__ unsigned long long packkey(float dv, int j) {
  unsigned ub = __float_as_uint(dv);
  ub ^= ((unsigned)((int)ub >> 31)) | 0x80000000u;   // monotone f32->u32
  return (((unsigned long long)ub) << 32) | (unsigned)j;
}
__device__ __forceinline__ float rfl(float v) {
  return __uint_as_float(__builtin_amdgcn_readfirstlane(__float_as_uint(v)));
}

__global__ __launch_bounds__(256, 3) void knn_kernel(
    const float* __restrict__ x, const float* __restrict__ sq,
    const float* __restrict__ P, const float* __restrict__ Q,
    int* __restrict__ idxOut, float* __restrict__ abuf) {
  __shared__ float sT16[CDIM][256];                 // transposed tile, 16 KB
  __shared__ float dB[32][256];                     // row-B dists, 32 KB
  __shared__ unsigned long long skey[4][64];        // per-wave survivor keys
  __shared__ int scnt[4];
  const int tid  = threadIdx.x;
  const int lane = tid & 63;
  const int w    = tid >> 6;
  const int blocksPerGraph = NPTS / KROWS;          // 256
  const int g     = blockIdx.x / blocksPerGraph;
  const int rb    = (blockIdx.x % blocksPerGraph) * KROWS;
  const int gbase = g * NPTS;
  const int r0    = rb + w*2;                       // rows r0 (A), r0+1 (B)

  // wave-uniform row features -> SGPRs
  float ta[CDIM], tb[CDIM]; float tsqA, tsqB;
  {
    const float4* tp = (const float4*)(x + (size_t)(gbase + r0)*CDIM);
    float4 t0 = tp[0], t1 = tp[1], t2 = tp[2], t3 = tp[3];
    ta[0]=rfl(t0.x);  ta[1]=rfl(t0.y);  ta[2]=rfl(t0.z);  ta[3]=rfl(t0.w);
    ta[4]=rfl(t1.x);  ta[5]=rfl(t1.y);  ta[6]=rfl(t1.z);  ta[7]=rfl(t1.w);
    ta[8]=rfl(t2.x);  ta[9]=rfl(t2.y);  ta[10]=rfl(t2.z); ta[11]=rfl(t2.w);
    ta[12]=rfl(t3.x); ta[13]=rfl(t3.y); ta[14]=rfl(t3.z); ta[15]=rfl(t3.w);
    tsqA = rfl(sq[gbase + r0]);
    const float4* up = (const float4*)(x + (size_t)(gbase + r0 + 1)*CDIM);
    float4 u0 = up[0], u1 = up[1], u2 = up[2], u3 = up[3];
    tb[0]=rfl(u0.x);  tb[1]=rfl(u0.y);  tb[2]=rfl(u0.z);  tb[3]=rfl(u0.w);
    tb[4]=rfl(u1.x);  tb[5]=rfl(u1.y);  tb[6]=rfl(u1.z);  tb[7]=rfl(u1.w);
    tb[8]=rfl(u2.x);  tb[9]=rfl(u2.y);  tb[10]=rfl(u2.z); tb[11]=rfl(u2.w);
    tb[12]=rfl(u3.x); tb[13]=rfl(u3.y); tb[14]=rfl(u3.z); tb[15]=rfl(u3.w);
    tsqB = rfl(sq[gbase + r0 + 1]);
  }

  float d[32];                                      // row A only (r1 shape)

  // prefetch tile 0 into regs (r1-proven staging structure)
  float4 a0, a1, a2, a3;
  {
    const float4* xp = (const float4*)(x + (size_t)(gbase + tid)*CDIM);
    a0 = xp[0]; a1 = xp[1]; a2 = xp[2]; a3 = xp[3];
  }

  #pragma unroll
  for (int t = 0; t < NPTS/256; ++t) {
    __syncthreads();                                // prev tile reads done
    sT16[0][tid]=a0.x;  sT16[1][tid]=a0.y;  sT16[2][tid]=a0.z;  sT16[3][tid]=a0.w;
    sT16[4][tid]=a1.x;  sT16[5][tid]=a1.y;  sT16[6][tid]=a1.z;  sT16[7][tid]=a1.w;
    sT16[8][tid]=a2.x;  sT16[9][tid]=a2.y;  sT16[10][tid]=a2.z; sT16[11][tid]=a2.w;
    sT16[12][tid]=a3.x; sT16[13][tid]=a3.y; sT16[14][tid]=a3.z; sT16[15][tid]=a3.w;
    __syncthreads();
    if (t < NPTS/256 - 1) {                         // issue next-tile loads early
      const float4* xp = (const float4*)(x + (size_t)(gbase + (t+1)*256 + tid)*CDIM);
      a0 = xp[0]; a1 = xp[1]; a2 = xp[2]; a3 = xp[3];
    }

    float4 sq4 = *(const float4*)(sq + gbase + t*256 + 4*lane);
    float sqv[4] = {sq4.x, sq4.y, sq4.z, sq4.w};

    float dotA[4] = {0.f,0.f,0.f,0.f};
    float dotB[4] = {0.f,0.f,0.f,0.f};
    #pragma unroll
    for (int c = 0; c < CDIM; ++c) {
      float4 cv = *(const float4*)(&sT16[c][4*lane]);   // shared by both rows
      float xa = ta[c], xb = tb[c];                 // SGPR operands
      dotA[0] += xa*cv.x; dotA[1] += xa*cv.y; dotA[2] += xa*cv.z; dotA[3] += xa*cv.w;
      dotB[0] += xb*cv.x; dotB[1] += xb*cv.y; dotB[2] += xb*cv.z; dotB[3] += xb*cv.w;
    }
    #pragma unroll
    for (int rr = 0; rr < 4; ++rr) {
      d[t*4 + rr] = tsqA + sqv[rr] - 2.f*dotA[rr];          // regs (row A)
      dB[t*4 + rr][tid] = tsqB + sqv[rr] - 2.f*dotB[rr];    // LDS  (row B)
    }
  }

  // -------- SELECT row A (registers — r1-proven body) --------
  {
    float lmin = d[0];
    #pragma unroll
    for (int s = 1; s < 32; ++s) lmin = fminf(lmin, d[s]);

    float v = lmin;
    #pragma unroll
    for (int k = 2; k <= 64; k <<= 1) {
      #pragma unroll
      for (int j = k >> 1; j > 0; j >>= 1) {
        float o = __shfl_xor(v, j);
        bool asc   = ((lane & k) == 0);
        bool lower = ((lane & j) == 0);
        float mn = fminf(v, o), mx = fmaxf(v, o);
        v = (asc == lower) ? mn : mx;
      }
    }
    float T = __shfl(v, 15);

    if (lane == 0) scnt[w] = 0;
    #pragma unroll
    for (int s = 0; s < 32; ++s) {
      if (d[s] <= T) {
        int p = atomicAdd(&scnt[w], 1);
        if (p < 64) {
          int j = (s >> 2)*256 + 4*lane + (s & 3);
          skey[w][p] = packkey(d[s], j);
        }
      }
    }
    int M = scnt[w];
    int row = gbase + r0;

    if (M <= 64) {
      unsigned long long key = (lane < M) ? skey[w][lane] : ~0ull;
      #pragma unroll
      for (int k = 2; k <= 64; k <<= 1) {
        #pragma unroll
        for (int j = k >> 1; j > 0; j >>= 1) {
          unsigned long long o = __shfl_xor(key, j);
          bool asc   = ((lane & k) == 0);
          bool lower = ((lane & j) == 0);
          unsigned long long mn = (key < o) ? key : o;
          unsigned long long mx = (key < o) ? o : key;
          key = (asc == lower) ? mn : mx;
        }
      }
      if (lane < KNN)
        idxOut[(size_t)row*KNN + lane] = gbase + (int)(key & 0xffffffffu);
    } else {
      for (int sel = 0; sel < KNN; ++sel) {
        unsigned long long lb = ~0ull;
        #pragma unroll
        for (int s = 0; s < 32; ++s) {
          int j = (s >> 2)*256 + 4*lane + (s & 3);
          unsigned long long ks = packkey(d[s], j);
          if (ks < lb) lb = ks;
        }
        #pragma unroll
        for (int off = 32; off > 0; off >>= 1) {
          unsigned long long o = __shfl_xor(lb, off);
          if (o < lb) lb = o;
        }
        if (lane == 0)
          idxOut[(size_t)row*KNN + sel] = gbase + (int)(lb & 0xffffffffu);
        #pragma unroll
        for (int s = 0; s < 32; ++s) {
          int j = (s >> 2)*256 + 4*lane + (s & 3);
          if (packkey(d[s], j) == lb) d[s] = FLT_MAX;
        }
      }
    }
  }

  // -------- SELECT row B (distances in dB[s][tid], same algorithm) --------
  {
    float lmin = dB[0][tid];
    #pragma unroll
    for (int s = 1; s < 32; ++s) lmin = fminf(lmin, dB[s][tid]);

    float v = lmin;
    #pragma unroll
    for (int k = 2; k <= 64; k <<= 1) {
      #pragma unroll
      for (int j = k >> 1; j > 0; j >>= 1) {
        float o = __shfl_xor(v, j);
        bool asc   = ((lane & k) == 0);
        bool lower = ((lane & j) == 0);
        float mn = fminf(v, o), mx = fmaxf(v, o);
        v = (asc == lower) ? mn : mx;
      }
    }
    float T = __shfl(v, 15);

    if (lane == 0) scnt[w] = 0;
    #pragma unroll
    for (int s = 0; s < 32; ++s) {
      float dv = dB[s][tid];
      if (dv <= T) {
        int p = atomicAdd(&scnt[w], 1);
        if (p < 64) {
          int j = (s >> 2)*256 + 4*lane + (s & 3);
          skey[w][p] = packkey(dv, j);
        }
      }
    }
    int M = scnt[w];
    int row = gbase + r0 + 1;

    if (M <= 64) {
      unsigned long long key = (lane < M) ? skey[w][lane] : ~0ull;
      #pragma unroll
      for (int k = 2; k <= 64; k <<= 1) {
        #pragma unroll
        for (int j = k >> 1; j > 0; j >>= 1) {
          unsigned long long o = __shfl_xor(key, j);
          bool asc   = ((lane & k) == 0);
          bool lower = ((lane & j) == 0);
          unsigned long long mn = (key < o) ? key : o;
          unsigned long long mx = (key < o) ? o : key;
          key = (asc == lower) ? mn : mx;
        }
      }
      if (lane < KNN)
        idxOut[(size_t)row*KNN + lane] = gbase + (int)(key & 0xffffffffu);
    } else {
      for (int sel = 0; sel < KNN; ++sel) {
        unsigned long long lb = ~0ull;
        #pragma unroll
        for (int s = 0; s < 32; ++s) {
          int j = (s >> 2)*256 + 4*lane + (s & 3);
          unsigned long long ks = packkey(dB[s][tid], j);
          if (ks < lb) lb = ks;
        }
        #pragma unroll
        for (int off = 32; off > 0; off >>= 1) {
          unsigned long long o = __shfl_xor(lb, off);
          if (o < lb) lb = o;
        }
        if (lane == 0)
          idxOut[(size_t)row*KNN + sel] = gbase + (int)(lb & 0xffffffffu);
        #pragma unroll
        for (int s = 0; s < 32; ++s) {
          int j = (s >> 2)*256 + 4*lane + (s & 3);
          if (packkey(dB[s][tid], j) == lb) dB[s][tid] = FLT_MAX;
        }
      }
    }
  }

  // -------- fused stats1 epilogue: h sum/sumsq for this wave's 2 rows ------
  // Grouped layout (= stats1a): grp owns edge-quad, lane owns 4 channels.
  // Indices re-read from idxOut (same-wave RAW via L2; both paths wrote it).
  __syncthreads();                       // all waves done with dB -> reuse
  {
    const int grp = lane >> 4;
    const int p   = lane & 15;
    float4 s4  = {0.f,0.f,0.f,0.f};
    float4 ss4 = {0.f,0.f,0.f,0.f};
    #pragma unroll
    for (int rp = 0; rp < 2; ++rp) {
      int row = gbase + r0 + rp;
      float4 q4 = *(const float4*)(Q + (size_t)row*ODIM + 4*p);
      int4 j4 = *(const int4*)(idxOut + (size_t)row*KNN + 4*grp);
      float4 v0 = *(const float4*)(P + (size_t)j4.x*ODIM + 4*p);
      float4 v1 = *(const float4*)(P + (size_t)j4.y*ODIM + 4*p);
      float4 v2 = *(const float4*)(P + (size_t)j4.z*ODIM + 4*p);
      float4 v3 = *(const float4*)(P + (size_t)j4.w*ODIM + 4*p);
      {
        float hx=q4.x+v0.x, hy=q4.y+v0.y, hz=q4.z+v0.z, hw=q4.w+v0.w;
        s4.x+=hx; s4.y+=hy; s4.z+=hz; s4.w+=hw;
        ss4.x+=hx*hx; ss4.y+=hy*hy; ss4.z+=hz*hz; ss4.w+=hw*hw;
      }
      {
        float hx=q4.x+v1.x, hy=q4.y+v1.y, hz=q4.z+v1.z, hw=q4.w+v1.w;
        s4.x+=hx; s4.y+=hy; s4.z+=hz; s4.w+=hw;
        ss4.x+=hx*hx; ss4.y+=hy*hy; ss4.z+=hz*hz; ss4.w+=hw*hw;
      }
      {
        float hx=q4.x+v2.x, hy=q4.y+v2.y, hz=q4.z+v2.z, hw=q4.w+v2.w;
        s4.x+=hx; s4.y+=hy; s4.z+=hz; s4.w+=hw;
        ss4.x+=hx*hx; ss4.y+=hy*hy; ss4.z+=hz*hz; ss4.w+=hw*hw;
      }
      {
        float hx=q4.x+v3.x, hy=q4.y+v3.y, hz=q4.z+v3.z, hw=q4.w+v3.w;
        s4.x+=hx; s4.y+=hy; s4.z+=hz; s4.w+=hw;
        ss4.x+=hx*hx; ss4.y+=hy*hy; ss4.z+=hz*hz; ss4.w+=hw*hw;
      }
    }
    // cross-group reduce: each group's partial enters ONCE (r7 post-mortem)
    s4.x  += __shfl_xor(s4.x,16);  s4.x  += __shfl_xor(s4.x,32);
    s4.y  += __shfl_xor(s4.y,16);  s4.y  += __shfl_xor(s4.y,32);
    s4.z  += __shfl_xor(s4.z,16);  s4.z  += __shfl_xor(s4.z,32);
    s4.w  += __shfl_xor(s4.w,16);  s4.w  += __shfl_xor(s4.w,32);
    ss4.x += __shfl_xor(ss4.x,16); ss4.x += __shfl_xor(ss4.x,32);
    ss4.y += __shfl_xor(ss4.y,16); ss4.y += __shfl_xor(ss4.y,32);
    ss4.z += __shfl_xor(ss4.z,16); ss4.z += __shfl_xor(ss4.z,32);
    ss4.w += __shfl_xor(ss4.w,16); ss4.w += __shfl_xor(ss4.w,32);
    float* comb = &dB[0][0];          // reuse dead dB: [0..255]=s, [256..511]=ss
    if (grp == 0) {
      *(float4*)&comb[w*ODIM + 4*p]       = s4;
      *(float4*)&comb[256 + w*ODIM + 4*p] = ss4;
    }
    __syncthreads();
    if (tid < ODIM) {
      float a = comb[tid] + comb[64+tid] + comb[128+tid] + comb[192+tid];
      atomicAdd(&abuf[(blockIdx.x & (NSETS-1))*128 + tid], a);
    } else if (tid < 2*ODIM) {
      int o = tid - ODIM;
      float a = comb[256+o] + comb[256+64+o] + comb[256+128+o] + comb[256+192+o];
      atomicAdd(&abuf[(blockIdx.x & (NSETS-1))*128 + tid], a);
    }
  }
}

// ---------------- stats pass 2: BN prologue + batched gate pass -------------
// Node loads issued BEFORE the prologue barrier (fly under the abuf reduce).
__global__ __launch_bounds__(256, 4) void stats2a_kernel(
    const float* __restrict__ P, const float* __restrict__ Q,
    const int* __restrict__ idx,
    const float* __restrict__ g1, const float* __restrict__ be1,
    const float* __restrict__ Wg, const float* __restrict__ bg,
    const float* __restrict__ abuf, float* __restrict__ scale,
    float* __restrict__ shift, float* __restrict__ gtbuf,
    float* __restrict__ gacc) {
  int tid  = threadIdx.x;
  int lane = tid & 63;
  int wid  = tid >> 6;
  int grp  = lane >> 4;                 // edge-quad slot
  int p    = lane & 15;                 // channel quad
  int gw   = blockIdx.x * 4 + wid;
  int n0 = gw * NPW;
  // issue node loads first — they complete during the BN prologue
  float4 q4v[NPW]; int4 j4v[NPW];
  #pragma unroll
  for (int ii = 0; ii < NPW; ++ii) {
    int i = n0 + ii;
    q4v[ii] = *(const float4*)(Q + (size_t)i*ODIM + 4*p);
    j4v[ii] = *(const int4*)(idx + (size_t)i*KNN + 4*grp);
  }
  __shared__ __align__(16) float s_sc[ODIM], s_sh[ODIM];
  __shared__ float red[2*ODIM];
  if (tid < 2*ODIM) {
    float a = 0.f;
    #pragma unroll
    for (int t = 0; t < NSETS; ++t) a += abuf[t*128 + tid];   // deterministic order
    red[tid] = a;
  }
  __syncthreads();
  if (tid < ODIM) {
    float mu  = red[tid] / (float)NEDGE;
    float var = red[ODIM+tid] / (float)NEDGE - mu*mu;
    float inv = 1.0f / sqrtf(var + EPSBN);
    float sc = g1[tid] * inv;
    float sh = be1[tid] - mu * sc;
    s_sc[tid] = sc; s_sh[tid] = sh;
    if (blockIdx.x == 0) { scale[tid] = sc; shift[tid] = sh; }  // for final
  }
  __syncthreads();

  float4 sc4 = *(const float4*)&s_sc[4*p];
  float4 sh4 = *(const float4*)&s_sh[4*p];
  float4 wg4 = *(const float4*)(Wg + 4*p);
  float bgv = bg[0];
  float s = 0.f, ss = 0.f;
  #pragma unroll
  for (int ii = 0; ii < NPW; ++ii) {
    int i = n0 + ii;
    float4 q4 = q4v[ii];
    float4 pv[4];
    pv[0] = *(const float4*)(P + (size_t)j4v[ii].x*ODIM + 4*p);
    pv[1] = *(const float4*)(P + (size_t)j4v[ii].y*ODIM + 4*p);
    pv[2] = *(const float4*)(P + (size_t)j4v[ii].z*ODIM + 4*p);
    pv[3] = *(const float4*)(P + (size_t)j4v[ii].w*ODIM + 4*p);
    #pragma unroll
    for (int e = 0; e < 4; ++e) {
      float4 p4 = pv[e];
      float zx = (q4.x + p4.x)*sc4.x + sh4.x;
      float zy = (q4.y + p4.y)*sc4.y + sh4.y;
      float zz = (q4.z + p4.z)*sc4.z + sh4.z;
      float zw = (q4.w + p4.w)*sc4.w + sh4.w;
      float v = (zx/(1.f+expf(-zx)))*wg4.x
              + (zy/(1.f+expf(-zy)))*wg4.y
              + (zz/(1.f+expf(-zz)))*wg4.z
              + (zw/(1.f+expf(-zw)))*wg4.w;
      v += __shfl_xor(v, 1);
      v += __shfl_xor(v, 2);
      v += __shfl_xor(v, 4);
      v += __shfl_xor(v, 8);            // group-wide sum over 64 channels
      float gt = v + bgv;
      if (p == 0) gtbuf[(size_t)i*KNN + 4*grp + e] = gt;
      s += gt; ss += gt*gt;             // per-group partial
    }
  }
  // each group's total enters exactly once (xor16/32 cross groups only)
  s  += __shfl_xor(s, 16);  s  += __shfl_xor(s, 32);
  ss += __shfl_xor(ss, 16); ss += __shfl_xor(ss, 32);
  __shared__ float pw[4], pws[4];
  if (lane == 0) { pw[wid] = s; pws[wid] = ss; }
  __syncthreads();
  if (tid == 0) {
    int set = blockIdx.x & (NSETS-1);
    atomicAdd(&gacc[2*set],   pw[0]+pw[1]+pw[2]+pw[3]);
    atomicAdd(&gacc[2*set+1], pws[0]+pws[1]+pws[2]+pws[3]);
  }
}

// ---------------- final: 2 nodes/wave, batched loads ------------------------
__global__ __launch_bounds__(256, 4) void final_kernel(
    const float* __restrict__ P, const float* __restrict__ Q,
    const int* __restrict__ idx, const float* __restrict__ scale,
    const float* __restrict__ shift, const float* __restrict__ gtbuf,
    const float* __restrict__ gacc, const float* __restrict__ gg,
    const float* __restrict__ beg, float* __restrict__ out) {
  __shared__ float g2[2];
  if (threadIdx.x == 0) {
    float S = 0.f, SS = 0.f;
    #pragma unroll
    for (int t = 0; t < NSETS; ++t) { S += gacc[2*t]; SS += gacc[2*t+1]; }
    float mu  = S / (float)NEDGE;
    float var = SS / (float)NEDGE - mu*mu;
    float inv = 1.f / sqrtf(var + EPSBN);
    float sg = gg[0] * inv;
    g2[0] = sg; g2[1] = beg[0] - mu * sg;
  }
  __syncthreads();
  int lane = threadIdx.x & 63;
  int wid  = threadIdx.x >> 6;
  int grp  = lane >> 4;
  int p    = lane & 15;
  int iA = blockIdx.x * 8 + wid * 2;
  int iB = iA + 1;
  float4 sc4 = *(const float4*)(scale + 4*p);
  float4 sh4 = *(const float4*)(shift + 4*p);
  float gscale = g2[0], gshift = g2[1];
  // batched loads for BOTH nodes
  float4 qA = *(const float4*)(Q + (size_t)iA*ODIM + 4*p);
  float4 qB = *(const float4*)(Q + (size_t)iB*ODIM + 4*p);
  int4   jA = *(const int4*)(idx + (size_t)iA*KNN + 4*grp);
  int4   jB = *(const int4*)(idx + (size_t)iB*KNN + 4*grp);
  float4 gA = *(const float4*)(gtbuf + (size_t)iA*KNN + 4*grp);
  float4 gB = *(const float4*)(gtbuf + (size_t)iB*KNN + 4*grp);
  float4 pA0 = *(const float4*)(P + (size_t)jA.x*ODIM + 4*p);
  float4 pA1 = *(const float4*)(P + (size_t)jA.y*ODIM + 4*p);
  float4 pA2 = *(const float4*)(P + (size_t)jA.z*ODIM + 4*p);
  float4 pA3 = *(const float4*)(P + (size_t)jA.w*ODIM + 4*p);
  float4 pB0 = *(const float4*)(P + (size_t)jB.x*ODIM + 4*p);
  float4 pB1 = *(const float4*)(P + (size_t)jB.y*ODIM + 4*p);
  float4 pB2 = *(const float4*)(P + (size_t)jB.z*ODIM + 4*p);
  float4 pB3 = *(const float4*)(P + (size_t)jB.w*ODIM + 4*p);

  // ---- node A ----
  {
    float z0 = gA.x*gscale + gshift, z1 = gA.y*gscale + gshift;
    float z2 = gA.z*gscale + gshift, z3 = gA.w*gscale + gshift;
    float gt0 = z0/(1.f+expf(-z0)), gt1 = z1/(1.f+expf(-z1));
    float gt2 = z2/(1.f+expf(-z2)), gt3 = z3/(1.f+expf(-z3));
    float m = fmaxf(fmaxf(gt0, gt1), fmaxf(gt2, gt3));
    m = fmaxf(m, __shfl_xor(m, 16));
    m = fmaxf(m, __shfl_xor(m, 32));
    float e0 = expf(gt0-m), e1 = expf(gt1-m), e2 = expf(gt2-m), e3 = expf(gt3-m);
    float se = e0+e1+e2+e3;
    se += __shfl_xor(se, 16);
    se += __shfl_xor(se, 32);
    float invs = 1.f / se;
    float a0 = e0*invs, a1 = e1*invs, a2 = e2*invs, a3 = e3*invs;
    float4 acc = {0.f,0.f,0.f,0.f};
    {
      float zx=(qA.x+pA0.x)*sc4.x+sh4.x, zy=(qA.y+pA0.y)*sc4.y+sh4.y;
      float zz=(qA.z+pA0.z)*sc4.z+sh4.z, zw=(qA.w+pA0.w)*sc4.w+sh4.w;
      acc.x += a0*(zx/(1.f+expf(-zx))); acc.y += a0*(zy/(1.f+expf(-zy)));
      acc.z += a0*(zz/(1.f+expf(-zz))); acc.w += a0*(zw/(1.f+expf(-zw)));
    }
    {
      float zx=(qA.x+pA1.x)*sc4.x+sh4.x, zy=(qA.y+pA1.y)*sc4.y+sh4.y;
      float zz=(qA.z+pA1.z)*sc4.z+sh4.z, zw=(qA.w+pA1.w)*sc4.w+sh4.w;
      acc.x += a1*(zx/(1.f+expf(-zx))); acc.y += a1*(zy/(1.f+expf(-zy)));
      acc.z += a1*(zz/(1.f+expf(-zz))); acc.w += a1*(zw/(1.f+expf(-zw)));
    }
    {
      float zx=(qA.x+pA2.x)*sc4.x+sh4.x, zy=(qA.y+pA2.y)*sc4.y+sh4.y;
      float zz=(qA.z+pA2.z)*sc4.z+sh4.z, zw=(qA.w+pA2.w)*sc4.w+sh4.w;
      acc.x += a2*(zx/(1.f+expf(-zx))); acc.y += a2*(zy/(1.f+expf(-zy)));
      acc.z += a2*(zz/(1.f+expf(-zz))); acc.w += a2*(zw/(1.f+expf(-zw)));
    }
    {
      float zx=(qA.x+pA3.x)*sc4.x+sh4.x, zy=(qA.y+pA3.y)*sc4.y+sh4.y;
      float zz=(qA.z+pA3.z)*sc4.z+sh4.z, zw=(qA.w+pA3.w)*sc4.w+sh4.w;
      acc.x += a3*(zx/(1.f+expf(-zx))); acc.y += a3*(zy/(1.f+expf(-zy)));
      acc.z += a3*(zz/(1.f+expf(-zz))); acc.w += a3*(zw/(1.f+expf(-zw)));
    }
    acc.x += __shfl_xor(acc.x,16); acc.x += __shfl_xor(acc.x,32);
    acc.y += __shfl_xor(acc.y,16); acc.y += __shfl_xor(acc.y,32);
    acc.z += __shfl_xor(acc.z,16); acc.z += __shfl_xor(acc.z,32);
    acc.w += __shfl_xor(acc.w,16); acc.w += __shfl_xor(acc.w,32);
    if (grp == 0)
      *(float4*)(out + (size_t)iA*ODIM + 4*p) = acc;
  }

  // ---- node B ----
  {
    float z0 = gB.x*gscale + gshift, z1 = gB.y*gscale + gshift;
    float z2 = gB.z*gscale + gshift, z3 = gB.w*gscale + gshift;
    float gt0 = z0/(1.f+expf(-z0)), gt1 = z1/(1.f+expf(-z1));
    float gt2 = z2/(1.f+expf(-z2)), gt3 = z3/(1.f+expf(-z3));
    float m = fmaxf(fmaxf(gt0, gt1), fmaxf(gt2, gt3));
    m = fmaxf(m, __shfl_xor(m, 16));
    m = fmaxf(m, __shfl_xor(m, 32));
    float e0 = expf(gt0-m), e1 = expf(gt1-m), e2 = expf(gt2-m), e3 = expf(gt3-m);
    float se = e0+e1+e2+e3;
    se += __shfl_xor(se, 16);
    se += __shfl_xor(se, 32);
    float invs = 1.f / se;
    float a0 = e0*invs, a1 = e1*invs, a2 = e2*invs, a3 = e3*invs;
    float4 acc = {0.f,0.f,0.f,0.f};
    {
      float zx=(qB.x+pB0.x)*sc4.x+sh4.x, zy=(qB.y+pB0.y)*sc4.y+sh4.y;
      float zz=(qB.z+pB0.z)*sc4.z+sh4.z, zw=(qB.w+pB0.w)*sc4.w+sh4.w;
      acc.x += a0*(zx/(1.f+expf(-zx))); acc.y += a0*(zy/(1.f+expf(-zy)));
      acc.z += a0*(zz/(1.f+expf(-zz))); acc.w += a0*(zw/(1.f+expf(-zw)));
    }
    {
      float zx=(qB.x+pB1.x)*sc4.x+sh4.x, zy=(qB.y+pB1.y)*sc4.y+sh4.y;
      float zz=(qB.z+pB1.z)*sc4.z+sh4.z, zw=(qB.w+pB1.w)*sc4.w+sh4.w;
      acc.x += a1*(zx/(1.f+expf(-zx))); acc.y += a1*(zy/(1.f+expf(-zy)));
      acc.z += a1*(zz/(1.f+expf(-zz))); acc.w += a1*(zw/(1.f+expf(-zw)));
    }
    {
      float zx=(qB.x+pB2.x)*sc4.x+sh4.x, zy=(qB.y+pB2.y)*sc4.y+sh4.y;
      float zz=(qB.z+pB2.z)*sc4.z+sh4.z, zw=(qB.w+pB2.w)*sc4.w+sh4.w;
      acc.x += a2*(zx/(1.f+expf(-zx))); acc.y += a2*(zy/(1.f+expf(-zy)));
      acc.z += a2*(zz/(1.f+expf(-zz))); acc.w += a2*(zw/(1.f+expf(-zw)));
    }
    {
      float zx=(qB.x+pB3.x)*sc4.x+sh4.x, zy=(qB.y+pB3.y)*sc4.y+sh4.y;
      float zz=(qB.z+pB3.z)*sc4.z+sh4.z, zw=(qB.w+pB3.w)*sc4.w+sh4.w;
      acc.x += a3*(zx/(1.f+expf(-zx))); acc.y += a3*(zy/(1.f+expf(-zy)));
      acc.z += a3*(zz/(1.f+expf(-zz))); acc.w += a3*(zw/(1.f+expf(-zw)));
    }
    acc.x += __shfl_xor(acc.x,16); acc.x += __shfl_xor(acc.x,32);
    acc.y += __shfl_xor(acc.y,16); acc.y += __shfl_xor(acc.y,32);
    acc.z += __shfl_xor(acc.z,16); acc.z += __shfl_xor(acc.z,32);
    acc.w += __shfl_xor(acc.w,16); acc.w += __shfl_xor(acc.w,32);
    if (grp == 0)
      *(float4*)(out + (size_t)iB*ODIM + 4*p) = acc;
  }
}

extern "C" void kernel_launch(void* const* d_in, const int* in_sizes, int n_in,
                              void* d_out, int out_size, void* d_ws, size_t ws_size,
                              hipStream_t stream) {
  const float* x   = (const float*)d_in[0];
  // d_in[1] = batch (unused: sorted equal-size graphs)
  const float* W1  = (const float*)d_in[2];
  const float* b1  = (const float*)d_in[3];
  const float* g1  = (const float*)d_in[4];
  const float* be1 = (const float*)d_in[5];
  const float* Wg  = (const float*)d_in[6];
  const float* bg  = (const float*)d_in[7];
  const float* gg  = (const float*)d_in[8];
  const float* beg = (const float*)d_in[9];
  float* out = (float*)d_out;

  char* ws = (char*)d_ws;
  int*   idx   = (int*)  (ws);                         // 2 MB
  float* P     = (float*)(ws + 2097152);               // 8 MB
  float* Q     = (float*)(ws + 10485760);              // 8 MB
  float* sq    = (float*)(ws + 18874368);              // 128 KB
  float* abuf  = (float*)(ws + 19005440);              // 16x128 f + 32 f
  float* gacc  = abuf + NSETS*128;                     // 32 f
  float* gtbuf = (float*)(ws + 20070400);              // 2 MB   [NEDGE]
  float* scale = (float*)(ws + 22167552);              // 64 f
  float* shift = (float*)(ws + 22167808);              // 64 f

  pq_kernel<<<NTOT/4, 256, 0, stream>>>(x, W1, b1, P, Q, sq, abuf);
  knn_kernel<<<NTOT/KROWS, 256, 0, stream>>>(x, sq, P, Q, idx, abuf);
  stats2a_kernel<<<NBLK_E, 256, 0, stream>>>(P, Q, idx, g1, be1, Wg, bg, abuf, scale, shift, gtbuf, gacc);
  final_kernel<<<NTOT/8, 256, 0, stream>>>(P, Q, idx, scale, shift, gtbuf, gacc, gg, beg, out);
}

// Round 16
// 262.201 us; speedup vs baseline: 2.8421x; 1.0252x over previous
//
#include <hip/hip_runtime.h>
#include <math.h>
#include <float.h>

#define BGRAPH 16
#define NPTS   2048
#define CDIM   16
#define ODIM   64
#define KNN    16
#define NTOT   (BGRAPH*NPTS)     // 32768
#define NEDGE  (NTOT*KNN)        // 524288
#define EPSBN  1e-5f
#define NBLK_E 2048              // blocks for edge-stat passes
#define NPW    4                 // nodes per wave in edge-stat passes
#define NSETS  16                // accumulator stripes

// SYNC LESSONS (r10-r12): coop grid.sync ~100us/sync; per-block threadfence
// ~250us; kernel boundary ~0.4us; striped atomicAdd + next dispatch = free.
// BUDGET (r15 calibration): ~85us fixed harness overhead in dur_us; kernel
// work ~182us = knn 121 + stats2a ~30 + final ~25 + pq ~5.
// r16: dB layout [32][256]->[256][33] (pad keeps banks conflict-free);
// scalar b32 LDS traffic -> b128 (saves ~270 of ~3300 LDS cyc/wave).

// ---------------- P = x@W1b, Q = x@(W1a-W1b)+b1, sq = rowsum(x*x) ----------
__global__ __launch_bounds__(256) void pq_kernel(
    const float* __restrict__ x, const float* __restrict__ W1,
    const float* __restrict__ b1,
    float* __restrict__ P, float* __restrict__ Q, float* __restrict__ sq,
    float* __restrict__ abuf) {
  if (blockIdx.x == 0) {
    for (int t = threadIdx.x; t < NSETS*128 + 2*NSETS; t += 256) abuf[t] = 0.f;
  }
  int lane = threadIdx.x & 63;
  int nin  = threadIdx.x >> 6;           // node within block (0..3)
  int node = blockIdx.x * 4 + nin;
  __shared__ float xs[4][CDIM];
  if (threadIdx.x < 4*CDIM) {
    int n = threadIdx.x / CDIM, c = threadIdx.x % CDIM;
    xs[n][c] = x[(blockIdx.x*4 + n)*CDIM + c];
  }
  __syncthreads();
  float p = 0.f, q = b1[lane];
  #pragma unroll
  for (int c = 0; c < CDIM; ++c) {
    float xv = xs[nin][c];
    float wb = W1[(c+CDIM)*ODIM + lane];
    float wa = W1[c*ODIM + lane];
    p += xv * wb;
    q += xv * (wa - wb);
  }
  P[node*ODIM + lane] = p;
  Q[node*ODIM + lane] = q;
  if (lane == 0) {
    float s = 0.f;
    #pragma unroll
    for (int c = 0; c < CDIM; ++c) { float xv = xs[nin][c]; s += xv*xv; }
    sq[node] = s;
  }
}

// ---------------- kNN (r13 body) + fused stats1 epilogue + dBr layout -------
// Row A d[32] in regs (r1 shape); row B in LDS dBr[tid][33] (pad -> bank
// (tid+s)%32, conflict-free for b128 row access AND per-s column access).
// Writes: 8 ds_write_b128/thread (was 32 b32). Selection reads: 16
// ds_read_b128 (was 64 b32). REVERT RULE: knn>125us or WRITE>10MB -> r15.
#define KROWS 8
__device__ __forceinline__ unsigned long long packkey(float dv, int j) {
  unsigned ub = __float_as_uint(dv);
  ub ^= ((unsigned)((int)ub >> 31)) | 0x80000000u;   // monotone f32->u32
  return (((unsigned long long)ub) << 32) | (unsigned)j;
}
__device__ __forceinline__ float rfl(float v) {
  return __uint_as_float(__builtin_amdgcn_readfirstlane(__float_as_uint(v)));
}

__global__ __launch_bounds__(256, 3) void knn_kernel(
    const float* __restrict__ x, const float* __restrict__ sq,
    const float* __restrict__ P, const float* __restrict__ Q,
    int* __restrict__ idxOut, float* __restrict__ abuf) {
  __shared__ float sT16[CDIM][256];                 // transposed tile, 16 KB
  __shared__ float dBr[256][33];                    // row-B dists, 33.8 KB
  __shared__ unsigned long long skey[4][64];        // per-wave survivor keys
  __shared__ int scnt[4];
  const int tid  = threadIdx.x;
  const int lane = tid & 63;
  const int w    = tid >> 6;
  const int blocksPerGraph = NPTS / KROWS;          // 256
  const int g     = blockIdx.x / blocksPerGraph;
  const int rb    = (blockIdx.x % blocksPerGraph) * KROWS;
  const int gbase = g * NPTS;
  const int r0    = rb + w*2;                       // rows r0 (A), r0+1 (B)

  // wave-uniform row features -> SGPRs
  float ta[CDIM], tb[CDIM]; float tsqA, tsqB;
  {
    const float4* tp = (const float4*)(x + (size_t)(gbase + r0)*CDIM);
    float4 t0 = tp[0], t1 = tp[1], t2 = tp[2], t3 = tp[3];
    ta[0]=rfl(t0.x);  ta[1]=rfl(t0.y);  ta[2]=rfl(t0.z);  ta[3]=rfl(t0.w);
    ta[4]=rfl(t1.x);  ta[5]=rfl(t1.y);  ta[6]=rfl(t1.z);  ta[7]=rfl(t1.w);
    ta[8]=rfl(t2.x);  ta[9]=rfl(t2.y);  ta[10]=rfl(t2.z); ta[11]=rfl(t2.w);
    ta[12]=rfl(t3.x); ta[13]=rfl(t3.y); ta[14]=rfl(t3.z); ta[15]=rfl(t3.w);
    tsqA = rfl(sq[gbase + r0]);
    const float4* up = (const float4*)(x + (size_t)(gbase + r0 + 1)*CDIM);
    float4 u0 = up[0], u1 = up[1], u2 = up[2], u3 = up[3];
    tb[0]=rfl(u0.x);  tb[1]=rfl(u0.y);  tb[2]=rfl(u0.z);  tb[3]=rfl(u0.w);
    tb[4]=rfl(u1.x);  tb[5]=rfl(u1.y);  tb[6]=rfl(u1.z);  tb[7]=rfl(u1.w);
    tb[8]=rfl(u2.x);  tb[9]=rfl(u2.y);  tb[10]=rfl(u2.z); tb[11]=rfl(u2.w);
    tb[12]=rfl(u3.x); tb[13]=rfl(u3.y); tb[14]=rfl(u3.z); tb[15]=rfl(u3.w);
    tsqB = rfl(sq[gbase + r0 + 1]);
  }

  float d[32];                                      // row A only (r1 shape)

  // prefetch tile 0 into regs (r1-proven staging structure)
  float4 a0, a1, a2, a3;
  {
    const float4* xp = (const float4*)(x + (size_t)(gbase + tid)*CDIM);
    a0 = xp[0]; a1 = xp[1]; a2 = xp[2]; a3 = xp[3];
  }

  #pragma unroll
  for (int t = 0; t < NPTS/256; ++t) {
    __syncthreads();                                // prev tile reads done
    sT16[0][tid]=a0.x;  sT16[1][tid]=a0.y;  sT16[2][tid]=a0.z;  sT16[3][tid]=a0.w;
    sT16[4][tid]=a1.x;  sT16[5][tid]=a1.y;  sT16[6][tid]=a1.z;  sT16[7][tid]=a1.w;
    sT16[8][tid]=a2.x;  sT16[9][tid]=a2.y;  sT16[10][tid]=a2.z; sT16[11][tid]=a2.w;
    sT16[12][tid]=a3.x; sT16[13][tid]=a3.y; sT16[14][tid]=a3.z; sT16[15][tid]=a3.w;
    __syncthreads();
    if (t < NPTS/256 - 1) {                         // issue next-tile loads early
      const float4* xp = (const float4*)(x + (size_t)(gbase + (t+1)*256 + tid)*CDIM);
      a0 = xp[0]; a1 = xp[1]; a2 = xp[2]; a3 = xp[3];
    }

    float4 sq4 = *(const float4*)(sq + gbase + t*256 + 4*lane);
    float sqv[4] = {sq4.x, sq4.y, sq4.z, sq4.w};

    float dotA[4] = {0.f,0.f,0.f,0.f};
    float dotB[4] = {0.f,0.f,0.f,0.f};
    #pragma unroll
    for (int c = 0; c < CDIM; ++c) {
      float4 cv = *(const float4*)(&sT16[c][4*lane]);   // shared by both rows
      float xa = ta[c], xb = tb[c];                 // SGPR operands
      dotA[0] += xa*cv.x; dotA[1] += xa*cv.y; dotA[2] += xa*cv.z; dotA[3] += xa*cv.w;
      dotB[0] += xb*cv.x; dotB[1] += xb*cv.y; dotB[2] += xb*cv.z; dotB[3] += xb*cv.w;
    }
    #pragma unroll
    for (int rr = 0; rr < 4; ++rr)
      d[t*4 + rr] = tsqA + sqv[rr] - 2.f*dotA[rr];          // regs (row A)
    float4 db4;
    db4.x = tsqB + sqv[0] - 2.f*dotB[0];
    db4.y = tsqB + sqv[1] - 2.f*dotB[1];
    db4.z = tsqB + sqv[2] - 2.f*dotB[2];
    db4.w = tsqB + sqv[3] - 2.f*dotB[3];
    *(float4*)&dBr[tid][t*4] = db4;                        // one b128 write
  }

  // -------- SELECT row A (registers — r1-proven body) --------
  {
    float lmin = d[0];
    #pragma unroll
    for (int s = 1; s < 32; ++s) lmin = fminf(lmin, d[s]);

    float v = lmin;
    #pragma unroll
    for (int k = 2; k <= 64; k <<= 1) {
      #pragma unroll
      for (int j = k >> 1; j > 0; j >>= 1) {
        float o = __shfl_xor(v, j);
        bool asc   = ((lane & k) == 0);
        bool lower = ((lane & j) == 0);
        float mn = fminf(v, o), mx = fmaxf(v, o);
        v = (asc == lower) ? mn : mx;
      }
    }
    float T = __shfl(v, 15);

    if (lane == 0) scnt[w] = 0;
    #pragma unroll
    for (int s = 0; s < 32; ++s) {
      if (d[s] <= T) {
        int p = atomicAdd(&scnt[w], 1);
        if (p < 64) {
          int j = (s >> 2)*256 + 4*lane + (s & 3);
          skey[w][p] = packkey(d[s], j);
        }
      }
    }
    int M = scnt[w];
    int row = gbase + r0;

    if (M <= 64) {
      unsigned long long key = (lane < M) ? skey[w][lane] : ~0ull;
      #pragma unroll
      for (int k = 2; k <= 64; k <<= 1) {
        #pragma unroll
        for (int j = k >> 1; j > 0; j >>= 1) {
          unsigned long long o = __shfl_xor(key, j);
          bool asc   = ((lane & k) == 0);
          bool lower = ((lane & j) == 0);
          unsigned long long mn = (key < o) ? key : o;
          unsigned long long mx = (key < o) ? o : key;
          key = (asc == lower) ? mn : mx;
        }
      }
      if (lane < KNN)
        idxOut[(size_t)row*KNN + lane] = gbase + (int)(key & 0xffffffffu);
    } else {
      for (int sel = 0; sel < KNN; ++sel) {
        unsigned long long lb = ~0ull;
        #pragma unroll
        for (int s = 0; s < 32; ++s) {
          int j = (s >> 2)*256 + 4*lane + (s & 3);
          unsigned long long ks = packkey(d[s], j);
          if (ks < lb) lb = ks;
        }
        #pragma unroll
        for (int off = 32; off > 0; off >>= 1) {
          unsigned long long o = __shfl_xor(lb, off);
          if (o < lb) lb = o;
        }
        if (lane == 0)
          idxOut[(size_t)row*KNN + sel] = gbase + (int)(lb & 0xffffffffu);
        #pragma unroll
        for (int s = 0; s < 32; ++s) {
          int j = (s >> 2)*256 + 4*lane + (s & 3);
          if (packkey(d[s], j) == lb) d[s] = FLT_MAX;
        }
      }
    }
  }

  // -------- SELECT row B (dBr[tid][s], b128 chunked reads) --------
  {
    float lmin = FLT_MAX;
    #pragma unroll
    for (int s0 = 0; s0 < 8; ++s0) {
      float4 v4 = *(const float4*)&dBr[tid][4*s0];
      lmin = fminf(lmin, fminf(fminf(v4.x, v4.y), fminf(v4.z, v4.w)));
    }

    float v = lmin;
    #pragma unroll
    for (int k = 2; k <= 64; k <<= 1) {
      #pragma unroll
      for (int j = k >> 1; j > 0; j >>= 1) {
        float o = __shfl_xor(v, j);
        bool asc   = ((lane & k) == 0);
        bool lower = ((lane & j) == 0);
        float mn = fminf(v, o), mx = fmaxf(v, o);
        v = (asc == lower) ? mn : mx;
      }
    }
    float T = __shfl(v, 15);

    if (lane == 0) scnt[w] = 0;
    #pragma unroll
    for (int s0 = 0; s0 < 8; ++s0) {
      float4 v4 = *(const float4*)&dBr[tid][4*s0];
      if (v4.x <= T) {
        int p = atomicAdd(&scnt[w], 1);
        if (p < 64) skey[w][p] = packkey(v4.x, s0*256 + 4*lane + 0);
      }
      if (v4.y <= T) {
        int p = atomicAdd(&scnt[w], 1);
        if (p < 64) skey[w][p] = packkey(v4.y, s0*256 + 4*lane + 1);
      }
      if (v4.z <= T) {
        int p = atomicAdd(&scnt[w], 1);
        if (p < 64) skey[w][p] = packkey(v4.z, s0*256 + 4*lane + 2);
      }
      if (v4.w <= T) {
        int p = atomicAdd(&scnt[w], 1);
        if (p < 64) skey[w][p] = packkey(v4.w, s0*256 + 4*lane + 3);
      }
    }
    int M = scnt[w];
    int row = gbase + r0 + 1;

    if (M <= 64) {
      unsigned long long key = (lane < M) ? skey[w][lane] : ~0ull;
      #pragma unroll
      for (int k = 2; k <= 64; k <<= 1) {
        #pragma unroll
        for (int j = k >> 1; j > 0; j >>= 1) {
          unsigned long long o = __shfl_xor(key, j);
          bool asc   = ((lane & k) == 0);
          bool lower = ((lane & j) == 0);
          unsigned long long mn = (key < o) ? key : o;
          unsigned long long mx = (key < o) ? o : key;
          key = (asc == lower) ? mn : mx;
        }
      }
      if (lane < KNN)
        idxOut[(size_t)row*KNN + lane] = gbase + (int)(key & 0xffffffffu);
    } else {
      for (int sel = 0; sel < KNN; ++sel) {
        unsigned long long lb = ~0ull;
        #pragma unroll
        for (int s0 = 0; s0 < 8; ++s0) {
          float4 v4 = *(const float4*)&dBr[tid][4*s0];
          unsigned long long k0 = packkey(v4.x, s0*256 + 4*lane + 0);
          unsigned long long k1 = packkey(v4.y, s0*256 + 4*lane + 1);
          unsigned long long k2 = packkey(v4.z, s0*256 + 4*lane + 2);
          unsigned long long k3 = packkey(v4.w, s0*256 + 4*lane + 3);
          if (k0 < lb) lb = k0;
          if (k1 < lb) lb = k1;
          if (k2 < lb) lb = k2;
          if (k3 < lb) lb = k3;
        }
        #pragma unroll
        for (int off = 32; off > 0; off >>= 1) {
          unsigned long long o = __shfl_xor(lb, off);
          if (o < lb) lb = o;
        }
        if (lane == 0)
          idxOut[(size_t)row*KNN + sel] = gbase + (int)(lb & 0xffffffffu);
        #pragma unroll
        for (int s0 = 0; s0 < 8; ++s0) {
          float4 v4 = *(const float4*)&dBr[tid][4*s0];
          if (packkey(v4.x, s0*256 + 4*lane + 0) == lb) dBr[tid][4*s0+0] = FLT_MAX;
          if (packkey(v4.y, s0*256 + 4*lane + 1) == lb) dBr[tid][4*s0+1] = FLT_MAX;
          if (packkey(v4.z, s0*256 + 4*lane + 2) == lb) dBr[tid][4*s0+2] = FLT_MAX;
          if (packkey(v4.w, s0*256 + 4*lane + 3) == lb) dBr[tid][4*s0+3] = FLT_MAX;
        }
      }
    }
  }

  // -------- fused stats1 epilogue: h sum/sumsq for this wave's 2 rows ------
  // Grouped layout (= stats1a): grp owns edge-quad, lane owns 4 channels.
  // Indices re-read from idxOut (same-wave RAW via L2; both paths wrote it).
  __syncthreads();                       // all waves done with dBr -> reuse
  {
    const int grp = lane >> 4;
    const int p   = lane & 15;
    float4 s4  = {0.f,0.f,0.f,0.f};
    float4 ss4 = {0.f,0.f,0.f,0.f};
    #pragma unroll
    for (int rp = 0; rp < 2; ++rp) {
      int row = gbase + r0 + rp;
      float4 q4 = *(const float4*)(Q + (size_t)row*ODIM + 4*p);
      int4 j4 = *(const int4*)(idxOut + (size_t)row*KNN + 4*grp);
      float4 v0 = *(const float4*)(P + (size_t)j4.x*ODIM + 4*p);
      float4 v1 = *(const float4*)(P + (size_t)j4.y*ODIM + 4*p);
      float4 v2 = *(const float4*)(P + (size_t)j4.z*ODIM + 4*p);
      float4 v3 = *(const float4*)(P + (size_t)j4.w*ODIM + 4*p);
      {
        float hx=q4.x+v0.x, hy=q4.y+v0.y, hz=q4.z+v0.z, hw=q4.w+v0.w;
        s4.x+=hx; s4.y+=hy; s4.z+=hz; s4.w+=hw;
        ss4.x+=hx*hx; ss4.y+=hy*hy; ss4.z+=hz*hz; ss4.w+=hw*hw;
      }
      {
        float hx=q4.x+v1.x, hy=q4.y+v1.y, hz=q4.z+v1.z, hw=q4.w+v1.w;
        s4.x+=hx; s4.y+=hy; s4.z+=hz; s4.w+=hw;
        ss4.x+=hx*hx; ss4.y+=hy*hy; ss4.z+=hz*hz; ss4.w+=hw*hw;
      }
      {
        float hx=q4.x+v2.x, hy=q4.y+v2.y, hz=q4.z+v2.z, hw=q4.w+v2.w;
        s4.x+=hx; s4.y+=hy; s4.z+=hz; s4.w+=hw;
        ss4.x+=hx*hx; ss4.y+=hy*hy; ss4.z+=hz*hz; ss4.w+=hw*hw;
      }
      {
        float hx=q4.x+v3.x, hy=q4.y+v3.y, hz=q4.z+v3.z, hw=q4.w+v3.w;
        s4.x+=hx; s4.y+=hy; s4.z+=hz; s4.w+=hw;
        ss4.x+=hx*hx; ss4.y+=hy*hy; ss4.z+=hz*hz; ss4.w+=hw*hw;
      }
    }
    // cross-group reduce: each group's partial enters ONCE (r7 post-mortem)
    s4.x  += __shfl_xor(s4.x,16);  s4.x  += __shfl_xor(s4.x,32);
    s4.y  += __shfl_xor(s4.y,16);  s4.y  += __shfl_xor(s4.y,32);
    s4.z  += __shfl_xor(s4.z,16);  s4.z  += __shfl_xor(s4.z,32);
    s4.w  += __shfl_xor(s4.w,16);  s4.w  += __shfl_xor(s4.w,32);
    ss4.x += __shfl_xor(ss4.x,16); ss4.x += __shfl_xor(ss4.x,32);
    ss4.y += __shfl_xor(ss4.y,16); ss4.y += __shfl_xor(ss4.y,32);
    ss4.z += __shfl_xor(ss4.z,16); ss4.z += __shfl_xor(ss4.z,32);
    ss4.w += __shfl_xor(ss4.w,16); ss4.w += __shfl_xor(ss4.w,32);
    float* comb = &dBr[0][0];         // reuse dead dBr: [0..255]=s, [256..511]=ss
    if (grp == 0) {
      *(float4*)&comb[w*ODIM + 4*p]       = s4;
      *(float4*)&comb[256 + w*ODIM + 4*p] = ss4;
    }
    __syncthreads();
    if (tid < ODIM) {
      float a = comb[tid] + comb[64+tid] + comb[128+tid] + comb[192+tid];
      atomicAdd(&abuf[(blockIdx.x & (NSETS-1))*128 + tid], a);
    } else if (tid < 2*ODIM) {
      int o = tid - ODIM;
      float a = comb[256+o] + comb[256+64+o] + comb[256+128+o] + comb[256+192+o];
      atomicAdd(&abuf[(blockIdx.x & (NSETS-1))*128 + tid], a);
    }
  }
}

// ---------------- stats pass 2: BN prologue + batched gate pass -------------
// Node loads issued BEFORE the prologue barrier (fly under the abuf reduce).
__global__ __launch_bounds__(256, 4) void stats2a_kernel(
    const float* __restrict__ P, const float* __restrict__ Q,
    const int* __restrict__ idx,
    const float* __restrict__ g1, const float* __restrict__ be1,
    const float* __restrict__ Wg, const float* __restrict__ bg,
    const float* __restrict__ abuf, float* __restrict__ scale,
    float* __restrict__ shift, float* __restrict__ gtbuf,
    float* __restrict__ gacc) {
  int tid  = threadIdx.x;
  int lane = tid & 63;
  int wid  = tid >> 6;
  int grp  = lane >> 4;                 // edge-quad slot
  int p    = lane & 15;                 // channel quad
  int gw   = blockIdx.x * 4 + wid;
  int n0 = gw * NPW;
  // issue node loads first — they complete during the BN prologue
  float4 q4v[NPW]; int4 j4v[NPW];
  #pragma unroll
  for (int ii = 0; ii < NPW; ++ii) {
    int i = n0 + ii;
    q4v[ii] = *(const float4*)(Q + (size_t)i*ODIM + 4*p);
    j4v[ii] = *(const int4*)(idx + (size_t)i*KNN + 4*grp);
  }
  __shared__ __align__(16) float s_sc[ODIM], s_sh[ODIM];
  __shared__ float red[2*ODIM];
  if (tid < 2*ODIM) {
    float a = 0.f;
    #pragma unroll
    for (int t = 0; t < NSETS; ++t) a += abuf[t*128 + tid];   // deterministic order
    red[tid] = a;
  }
  __syncthreads();
  if (tid < ODIM) {
    float mu  = red[tid] / (float)NEDGE;
    float var = red[ODIM+tid] / (float)NEDGE - mu*mu;
    float inv = 1.0f / sqrtf(var + EPSBN);
    float sc = g1[tid] * inv;
    float sh = be1[tid] - mu * sc;
    s_sc[tid] = sc; s_sh[tid] = sh;
    if (blockIdx.x == 0) { scale[tid] = sc; shift[tid] = sh; }  // for final
  }
  __syncthreads();

  float4 sc4 = *(const float4*)&s_sc[4*p];
  float4 sh4 = *(const float4*)&s_sh[4*p];
  float4 wg4 = *(const float4*)(Wg + 4*p);
  float bgv = bg[0];
  float s = 0.f, ss = 0.f;
  #pragma unroll
  for (int ii = 0; ii < NPW; ++ii) {
    int i = n0 + ii;
    float4 q4 = q4v[ii];
    float4 pv[4];
    pv[0] = *(const float4*)(P + (size_t)j4v[ii].x*ODIM + 4*p);
    pv[1] = *(const float4*)(P + (size_t)j4v[ii].y*ODIM + 4*p);
    pv[2] = *(const float4*)(P + (size_t)j4v[ii].z*ODIM + 4*p);
    pv[3] = *(const float4*)(P + (size_t)j4v[ii].w*ODIM + 4*p);
    #pragma unroll
    for (int e = 0; e < 4; ++e) {
      float4 p4 = pv[e];
      float zx = (q4.x + p4.x)*sc4.x + sh4.x;
      float zy = (q4.y + p4.y)*sc4.y + sh4.y;
      float zz = (q4.z + p4.z)*sc4.z + sh4.z;
      float zw = (q4.w + p4.w)*sc4.w + sh4.w;
      float v = (zx/(1.f+expf(-zx)))*wg4.x
              + (zy/(1.f+expf(-zy)))*wg4.y
              + (zz/(1.f+expf(-zz)))*wg4.z
              + (zw/(1.f+expf(-zw)))*wg4.w;
      v += __shfl_xor(v, 1);
      v += __shfl_xor(v, 2);
      v += __shfl_xor(v, 4);
      v += __shfl_xor(v, 8);            // group-wide sum over 64 channels
      float gt = v + bgv;
      if (p == 0) gtbuf[(size_t)i*KNN + 4*grp + e] = gt;
      s += gt; ss += gt*gt;             // per-group partial
    }
  }
  // each group's total enters exactly once (xor16/32 cross groups only)
  s  += __shfl_xor(s, 16);  s  += __shfl_xor(s, 32);
  ss += __shfl_xor(ss, 16); ss += __shfl_xor(ss, 32);
  __shared__ float pw[4], pws[4];
  if (lane == 0) { pw[wid] = s; pws[wid] = ss; }
  __syncthreads();
  if (tid == 0) {
    int set = blockIdx.x & (NSETS-1);
    atomicAdd(&gacc[2*set],   pw[0]+pw[1]+pw[2]+pw[3]);
    atomicAdd(&gacc[2*set+1], pws[0]+pws[1]+pws[2]+pws[3]);
  }
}

// ---------------- final: 2 nodes/wave, batched loads ------------------------
__global__ __launch_bounds__(256, 4) void final_kernel(
    const float* __restrict__ P, const float* __restrict__ Q,
    const int* __restrict__ idx, const float* __restrict__ scale,
    const float* __restrict__ shift, const float* __restrict__ gtbuf,
    const float* __restrict__ gacc, const float* __restrict__ gg,
    const float* __restrict__ beg, float* __restrict__ out) {
  __shared__ float g2[2];
  if (threadIdx.x == 0) {
    float S = 0.f, SS = 0.f;
    #pragma unroll
    for (int t = 0; t < NSETS; ++t) { S += gacc[2*t]; SS += gacc[2*t+1]; }
    float mu  = S / (float)NEDGE;
    float var = SS / (float)NEDGE - mu*mu;
    float inv = 1.f / sqrtf(var + EPSBN);
    float sg = gg[0] * inv;
    g2[0] = sg; g2[1] = beg[0] - mu * sg;
  }
  __syncthreads();
  int lane = threadIdx.x & 63;
  int wid  = threadIdx.x >> 6;
  int grp  = lane >> 4;
  int p    = lane & 15;
  int iA = blockIdx.x * 8 + wid * 2;
  int iB = iA + 1;
  float4 sc4 = *(const float4*)(scale + 4*p);
  float4 sh4 = *(const float4*)(shift + 4*p);
  float gscale = g2[0], gshift = g2[1];
  // batched loads for BOTH nodes
  float4 qA = *(const float4*)(Q + (size_t)iA*ODIM + 4*p);
  float4 qB = *(const float4*)(Q + (size_t)iB*ODIM + 4*p);
  int4   jA = *(const int4*)(idx + (size_t)iA*KNN + 4*grp);
  int4   jB = *(const int4*)(idx + (size_t)iB*KNN + 4*grp);
  float4 gA = *(const float4*)(gtbuf + (size_t)iA*KNN + 4*grp);
  float4 gB = *(const float4*)(gtbuf + (size_t)iB*KNN + 4*grp);
  float4 pA0 = *(const float4*)(P + (size_t)jA.x*ODIM + 4*p);
  float4 pA1 = *(const float4*)(P + (size_t)jA.y*ODIM + 4*p);
  float4 pA2 = *(const float4*)(P + (size_t)jA.z*ODIM + 4*p);
  float4 pA3 = *(const float4*)(P + (size_t)jA.w*ODIM + 4*p);
  float4 pB0 = *(const float4*)(P + (size_t)jB.x*ODIM + 4*p);
  float4 pB1 = *(const float4*)(P + (size_t)jB.y*ODIM + 4*p);
  float4 pB2 = *(const float4*)(P + (size_t)jB.z*ODIM + 4*p);
  float4 pB3 = *(const float4*)(P + (size_t)jB.w*ODIM + 4*p);

  // ---- node A ----
  {
    float z0 = gA.x*gscale + gshift, z1 = gA.y*gscale + gshift;
    float z2 = gA.z*gscale + gshift, z3 = gA.w*gscale + gshift;
    float gt0 = z0/(1.f+expf(-z0)), gt1 = z1/(1.f+expf(-z1));
    float gt2 = z2/(1.f+expf(-z2)), gt3 = z3/(1.f+expf(-z3));
    float m = fmaxf(fmaxf(gt0, gt1), fmaxf(gt2, gt3));
    m = fmaxf(m, __shfl_xor(m, 16));
    m = fmaxf(m, __shfl_xor(m, 32));
    float e0 = expf(gt0-m), e1 = expf(gt1-m), e2 = expf(gt2-m), e3 = expf(gt3-m);
    float se = e0+e1+e2+e3;
    se += __shfl_xor(se, 16);
    se += __shfl_xor(se, 32);
    float invs = 1.f / se;
    float a0 = e0*invs, a1 = e1*invs, a2 = e2*invs, a3 = e3*invs;
    float4 acc = {0.f,0.f,0.f,0.f};
    {
      float zx=(qA.x+pA0.x)*sc4.x+sh4.x, zy=(qA.y+pA0.y)*sc4.y+sh4.y;
      float zz=(qA.z+pA0.z)*sc4.z+sh4.z, zw=(qA.w+pA0.w)*sc4.w+sh4.w;
      acc.x += a0*(zx/(1.f+expf(-zx))); acc.y += a0*(zy/(1.f+expf(-zy)));
      acc.z += a0*(zz/(1.f+expf(-zz))); acc.w += a0*(zw/(1.f+expf(-zw)));
    }
    {
      float zx=(qA.x+pA1.x)*sc4.x+sh4.x, zy=(qA.y+pA1.y)*sc4.y+sh4.y;
      float zz=(qA.z+pA1.z)*sc4.z+sh4.z, zw=(qA.w+pA1.w)*sc4.w+sh4.w;
      acc.x += a1*(zx/(1.f+expf(-zx))); acc.y += a1*(zy/(1.f+expf(-zy)));
      acc.z += a1*(zz/(1.f+expf(-zz))); acc.w += a1*(zw/(1.f+expf(-zw)));
    }
    {
      float zx=(qA.x+pA2.x)*sc4.x+sh4.x, zy=(qA.y+pA2.y)*sc4.y+sh4.y;
      float zz=(qA.z+pA2.z)*sc4.z+sh4.z, zw=(qA.w+pA2.w)*sc4.w+sh4.w;
      acc.x += a2*(zx/(1.f+expf(-zx))); acc.y += a2*(zy/(1.f+expf(-zy)));
      acc.z += a2*(zz/(1.f+expf(-zz))); acc.w += a2*(zw/(1.f+expf(-zw)));
    }
    {
      float zx=(qA.x+pA3.x)*sc4.x+sh4.x, zy=(qA.y+pA3.y)*sc4.y+sh4.y;
      float zz=(qA.z+pA3.z)*sc4.z+sh4.z, zw=(qA.w+pA3.w)*sc4.w+sh4.w;
      acc.x += a3*(zx/(1.f+expf(-zx))); acc.y += a3*(zy/(1.f+expf(-zy)));
      acc.z += a3*(zz/(1.f+expf(-zz))); acc.w += a3*(zw/(1.f+expf(-zw)));
    }
    acc.x += __shfl_xor(acc.x,16); acc.x += __shfl_xor(acc.x,32);
    acc.y += __shfl_xor(acc.y,16); acc.y += __shfl_xor(acc.y,32);
    acc.z += __shfl_xor(acc.z,16); acc.z += __shfl_xor(acc.z,32);
    acc.w += __shfl_xor(acc.w,16); acc.w += __shfl_xor(acc.w,32);
    if (grp == 0)
      *(float4*)(out + (size_t)iA*ODIM + 4*p) = acc;
  }

  // ---- node B ----
  {
    float z0 = gB.x*gscale + gshift, z1 = gB.y*gscale + gshift;
    float z2 = gB.z*gscale + gshift, z3 = gB.w*gscale + gshift;
    float gt0 = z0/(1.f+expf(-z0)), gt1 = z1/(1.f+expf(-z1));
    float gt2 = z2/(1.f+expf(-z2)), gt3 = z3/(1.f+expf(-z3));
    float m = fmaxf(fmaxf(gt0, gt1), fmaxf(gt2, gt3));
    m = fmaxf(m, __shfl_xor(m, 16));
    m = fmaxf(m, __shfl_xor(m, 32));
    float e0 = expf(gt0-m), e1 = expf(gt1-m), e2 = expf(gt2-m), e3 = expf(gt3-m);
    float se = e0+e1+e2+e3;
    se += __shfl_xor(se, 16);
    se += __shfl_xor(se, 32);
    float invs = 1.f / se;
    float a0 = e0*invs, a1 = e1*invs, a2 = e2*invs, a3 = e3*invs;
    float4 acc = {0.f,0.f,0.f,0.f};
    {
      float zx=(qB.x+pB0.x)*sc4.x+sh4.x, zy=(qB.y+pB0.y)*sc4.y+sh4.y;
      float zz=(qB.z+pB0.z)*sc4.z+sh4.z, zw=(qB.w+pB0.w)*sc4.w+sh4.w;
      acc.x += a0*(zx/(1.f+expf(-zx))); acc.y += a0*(zy/(1.f+expf(-zy)));
      acc.z += a0*(zz/(1.f+expf(-zz))); acc.w += a0*(zw/(1.f+expf(-zw)));
    }
    {
      float zx=(qB.x+pB1.x)*sc4.x+sh4.x, zy=(qB.y+pB1.y)*sc4.y+sh4.y;
      float zz=(qB.z+pB1.z)*sc4.z+sh4.z, zw=(qB.w+pB1.w)*sc4.w+sh4.w;
      acc.x += a1*(zx/(1.f+expf(-zx))); acc.y += a1*(zy/(1.f+expf(-zy)));
      acc.z += a1*(zz/(1.f+expf(-zz))); acc.w += a1*(zw/(1.f+expf(-zw)));
    }
    {
      float zx=(qB.x+pB2.x)*sc4.x+sh4.x, zy=(qB.y+pB2.y)*sc4.y+sh4.y;
      float zz=(qB.z+pB2.z)*sc4.z+sh4.z, zw=(qB.w+pB2.w)*sc4.w+sh4.w;
      acc.x += a2*(zx/(1.f+expf(-zx))); acc.y += a2*(zy/(1.f+expf(-zy)));
      acc.z += a2*(zz/(1.f+expf(-zz))); acc.w += a2*(zw/(1.f+expf(-zw)));
    }
    {
      float zx=(qB.x+pB3.x)*sc4.x+sh4.x, zy=(qB.y+pB3.y)*sc4.y+sh4.y;
      float zz=(qB.z+pB3.z)*sc4.z+sh4.z, zw=(qB.w+pB3.w)*sc4.w+sh4.w;
      acc.x += a3*(zx/(1.f+expf(-zx))); acc.y += a3*(zy/(1.f+expf(-zy)));
      acc.z += a3*(zz/(1.f+expf(-zz))); acc.w += a3*(zw/(1.f+expf(-zw)));
    }
    acc.x += __shfl_xor(acc.x,16); acc.x += __shfl_xor(acc.x,32);
    acc.y += __shfl_xor(acc.y,16); acc.y += __shfl_xor(acc.y,32);
    acc.z += __shfl_xor(acc.z,16); acc.z += __shfl_xor(acc.z,32);
    acc.w += __shfl_xor(acc.w,16); acc.w += __shfl_xor(acc.w,32);
    if (grp == 0)
      *(float4*)(out + (size_t)iB*ODIM + 4*p) = acc;
  }
}

extern "C" void kernel_launch(void* const* d_in, const int* in_sizes, int n_in,
                              void* d_out, int out_size, void* d_ws, size_t ws_size,
                              hipStream_t stream) {
  const float* x   = (const float*)d_in[0];
  // d_in[1] = batch (unused: sorted equal-size graphs)
  const float* W1  = (const float*)d_in[2];
  const float* b1  = (const float*)d_in[3];
  const float* g1  = (const float*)d_in[4];
  const float* be1 = (const float*)d_in[5];
  const float* Wg  = (const float*)d_in[6];
  const float* bg  = (const float*)d_in[7];
  const float* gg  = (const float*)d_in[8];
  const float* beg = (const float*)d_in[9];
  float* out = (float*)d_out;

  char* ws = (char*)d_ws;
  int*   idx   = (int*)  (ws);                         // 2 MB
  float* P     = (float*)(ws + 2097152);               // 8 MB
  float* Q     = (float*)(ws + 10485760);              // 8 MB
  float* sq    = (float*)(ws + 18874368);              // 128 KB
  float* abuf  = (float*)(ws + 19005440);              // 16x128 f + 32 f
  float* gacc  = abuf + NSETS*128;                     // 32 f
  float* gtbuf = (float*)(ws + 20070400);              // 2 MB   [NEDGE]
  float* scale = (float*)(ws + 22167552);              // 64 f
  float* shift = (float*)(ws + 22167808);              // 64 f

  pq_kernel<<<NTOT/4, 256, 0, stream>>>(x, W1, b1, P, Q, sq, abuf);
  knn_kernel<<<NTOT/KROWS, 256, 0, stream>>>(x, sq, P, Q, idx, abuf);
  stats2a_kernel<<<NBLK_E, 256, 0, stream>>>(P, Q, idx, g1, be1, Wg, bg, abuf, scale, shift, gtbuf, gacc);
  final_kernel<<<NTOT/8, 256, 0, stream>>>(P, Q, idx, scale, shift, gtbuf, gacc, gg, beg, out);
}